// Round 1
// 1257.526 us; speedup vs baseline: 1.7118x; 1.7118x over previous
//
#include <hip/hip_runtime.h>
#include <math.h>

// Problem constants
#define NB 32          // batch
#define NC 1024        // channels
#define LTOT 680       // total tokens per batch
#define NCHUNK 90      // 8-token chunks across all scales (alpha kernel)

typedef unsigned short u16;
typedef __bf16 bf16x8 __attribute__((ext_vector_type(8)));
typedef float floatx4 __attribute__((ext_vector_type(4)));

__device__ __forceinline__ u16 f2bf(float f)
{
    union { float f; unsigned u; } v; v.f = f;
    unsigned u = v.u;
    u += 0x7FFFu + ((u >> 16) & 1u);   // RNE
    return (u16)(u >> 16);
}

__device__ __forceinline__ float bf2f(unsigned u)
{
    union { unsigned u; float f; } v; v.u = u << 16; return v.f;
}

// ---------------------------------------------------------------------------
// chunk -> (scale, l0, nq) lookup for alpha kernel (8-token chunks).
// ---------------------------------------------------------------------------
__device__ __forceinline__ void chunk_info(int chunk, int* pi, int* pl0, int* pnq)
{
    const int cb[10] = {0,1,2,4,6,10,15,23,36,58};
    const int sb[10] = {0,1,5,14,30,55,91,155,255,424};
    const int se[10] = {1,5,14,30,55,91,155,255,424,680};
    int ii = 0;
#pragma unroll
    for (int k = 1; k < 10; ++k) if (chunk >= cb[k]) ii = k;
    int l0 = sb[ii] + (chunk - cb[ii]) * 8;
    int nq = se[ii] - l0; if (nq > 8) nq = 8;
    *pi = ii; *pl0 = l0; *pnq = nq;
}

// ---------------------------------------------------------------------------
// bf16 MFMA GEMM (m97-style): C[MxN] fp32 = A[MxK] @ B, with B given as
// BT[NxK] bf16 row-major. 128x128 tile, BK=64, 256 threads = 4 waves in a
// 2x2 wave grid; each wave computes 4x4 frags of 16x16 (64x64 quadrant).
// LDS holds A/B tiles in FRAGMENT ORDER: [tile*2+kh][lane][8 bf16] so every
// ds_read/ds_write is lane-linear b128 (conflict-free).
// AFP32=1: A is fp32, cast to bf16 inline during staging.
// OUTBF=1: C stored as bf16 (u16) instead of fp32.
// M,N arbitrary (clamped loads, guarded stores); K multiple of 64.
// ---------------------------------------------------------------------------
template<int AFP32, int OUTBF>
__global__ __launch_bounds__(256) void gemm_mfma(
    const void* __restrict__ Av, const u16* __restrict__ BT,
    float* __restrict__ C, int M, int N, int K,
    const float* __restrict__ bias, const float* __restrict__ scale_logit)
{
    __shared__ __align__(16) u16 As[16 * 64 * 8];   // 16KB
    __shared__ __align__(16) u16 Bs[16 * 64 * 8];   // 16KB

    const int tid  = threadIdx.x;
    const int m0   = blockIdx.x << 7;
    const int n0   = blockIdx.y << 7;
    const int wave = tid >> 6;
    const int lane = tid & 63;
    const int mh   = wave & 1;
    const int nh   = wave >> 1;

    floatx4 acc[4][4];
#pragma unroll
    for (int i = 0; i < 4; ++i)
#pragma unroll
        for (int j = 0; j < 4; ++j) acc[i][j] = (floatx4){0.f, 0.f, 0.f, 0.f};

    for (int k0 = 0; k0 < K; k0 += 64) {
        __syncthreads();
        // ---- stage A tile (128 rows x 64 k) into frag order ----
        if (AFP32) {
            const float* A = (const float*)Av;
#pragma unroll
            for (int p = 0; p < 8; ++p) {
                int q   = tid + (p << 8);          // 2048 chunks of 4 floats
                int row = q >> 4;
                int fq  = q & 15;                  // 4-float chunk within row
                int gr  = m0 + row; if (gr > M - 1) gr = M - 1;
                const float4 a4 = *(const float4*)(A + (size_t)gr * K + k0 + (fq << 2));
                int kh = fq >> 3, quad = (fq >> 1) & 3, jh = fq & 1;
                u16* d = &As[((((row >> 4) << 1) | kh) * 64 + (quad << 4) + (row & 15)) * 8 + (jh << 2)];
                d[0] = f2bf(a4.x); d[1] = f2bf(a4.y); d[2] = f2bf(a4.z); d[3] = f2bf(a4.w);
            }
        } else {
            const u16* A = (const u16*)Av;
#pragma unroll
            for (int p = 0; p < 4; ++p) {
                int q   = tid + (p << 8);          // 1024 chunks of 8 bf16
                int row = q >> 3;
                int cq  = q & 7;
                int gr  = m0 + row; if (gr > M - 1) gr = M - 1;
                *(uint4*)&As[((((row >> 4) << 1) | (cq >> 2)) * 64 + ((cq & 3) << 4) + (row & 15)) * 8]
                    = *(const uint4*)(A + (size_t)gr * K + k0 + (cq << 3));
            }
        }
        // ---- stage B tile (BT rows = output cols) ----
#pragma unroll
        for (int p = 0; p < 4; ++p) {
            int q   = tid + (p << 8);
            int row = q >> 3;
            int cq  = q & 7;
            int gn  = n0 + row; if (gn > N - 1) gn = N - 1;
            *(uint4*)&Bs[((((row >> 4) << 1) | (cq >> 2)) * 64 + ((cq & 3) << 4) + (row & 15)) * 8]
                = *(const uint4*)(BT + (size_t)gn * K + k0 + (cq << 3));
        }
        __syncthreads();
        // ---- MFMA over the two K-halves ----
#pragma unroll
        for (int kh = 0; kh < 2; ++kh) {
            bf16x8 a[4], b[4];
#pragma unroll
            for (int i = 0; i < 4; ++i)
                a[i] = *(const bf16x8*)&As[(((((mh << 2) + i) << 1) | kh) * 64 + lane) * 8];
#pragma unroll
            for (int j = 0; j < 4; ++j)
                b[j] = *(const bf16x8*)&Bs[(((((nh << 2) + j) << 1) | kh) * 64 + lane) * 8];
#pragma unroll
            for (int i = 0; i < 4; ++i)
#pragma unroll
                for (int j = 0; j < 4; ++j)
                    acc[i][j] = __builtin_amdgcn_mfma_f32_16x16x32_bf16(a[i], b[j], acc[i][j], 0, 0, 0);
        }
    }

    float scale = 1.f;
    if (scale_logit) scale = 1.f / (1.f + __expf(-scale_logit[0]));
    const int col = lane & 15, rquad = lane >> 4;
#pragma unroll
    for (int i = 0; i < 4; ++i) {
#pragma unroll
        for (int j = 0; j < 4; ++j) {
#pragma unroll
            for (int r = 0; r < 4; ++r) {
                int gr = m0 + (mh << 6) + (i << 4) + (rquad << 2) + r;
                int gc = n0 + (nh << 6) + (j << 4) + col;
                if (gr < M && gc < N) {
                    float bb = bias ? bias[gc] : 0.f;
                    float val = scale * (acc[i][j][r] + bb);
                    if (OUTBF) ((u16*)C)[(size_t)gr * N + gc] = f2bf(val);
                    else       C[(size_t)gr * N + gc] = val;
                }
            }
        }
    }
}

// ---------------------------------------------------------------------------
// Batched logits GEMM: out[b][680][640] = Q_b[680x1024] @ [sk ; kc_b]^T.
// B row j (output col): j<320 -> sk_bf[j][1024] ; j>=320 -> kc_bf[b][j-320][1024].
// Same m97-style body as gemm_mfma (bf16 A path), M=680 N=640 K=1024.
// ---------------------------------------------------------------------------
__global__ __launch_bounds__(256) void gemm_logits(
    const u16* __restrict__ Q, const u16* __restrict__ skb,
    const u16* __restrict__ kcb, float* __restrict__ out)
{
    __shared__ __align__(16) u16 As[16 * 64 * 8];
    __shared__ __align__(16) u16 Bs[16 * 64 * 8];

    const int tid  = threadIdx.x;
    const int m0   = blockIdx.x << 7;
    const int n0   = blockIdx.y << 7;
    const int b    = blockIdx.z;
    const int wave = tid >> 6;
    const int lane = tid & 63;
    const int mh   = wave & 1;
    const int nh   = wave >> 1;

    const u16* Ab = Q   + (size_t)b * 680 * 1024;
    const u16* KC = kcb + (size_t)b * 320 * 1024;

    floatx4 acc[4][4];
#pragma unroll
    for (int i = 0; i < 4; ++i)
#pragma unroll
        for (int j = 0; j < 4; ++j) acc[i][j] = (floatx4){0.f, 0.f, 0.f, 0.f};

    for (int k0 = 0; k0 < 1024; k0 += 64) {
        __syncthreads();
#pragma unroll
        for (int p = 0; p < 4; ++p) {
            int q = tid + (p << 8);
            int row = q >> 3, cq = q & 7;
            int gr = m0 + row; if (gr > 679) gr = 679;
            *(uint4*)&As[((((row >> 4) << 1) | (cq >> 2)) * 64 + ((cq & 3) << 4) + (row & 15)) * 8]
                = *(const uint4*)(Ab + (size_t)gr * 1024 + k0 + (cq << 3));
        }
#pragma unroll
        for (int p = 0; p < 4; ++p) {
            int q = tid + (p << 8);
            int row = q >> 3, cq = q & 7;
            int gn = n0 + row;                    // < 640 always
            const u16* src = (gn < 320) ? (skb + (size_t)gn * 1024)
                                        : (KC + (size_t)(gn - 320) * 1024);
            *(uint4*)&Bs[((((row >> 4) << 1) | (cq >> 2)) * 64 + ((cq & 3) << 4) + (row & 15)) * 8]
                = *(const uint4*)(src + k0 + (cq << 3));
        }
        __syncthreads();
#pragma unroll
        for (int kh = 0; kh < 2; ++kh) {
            bf16x8 a[4], bb[4];
#pragma unroll
            for (int i = 0; i < 4; ++i)
                a[i] = *(const bf16x8*)&As[(((((mh << 2) + i) << 1) | kh) * 64 + lane) * 8];
#pragma unroll
            for (int j = 0; j < 4; ++j)
                bb[j] = *(const bf16x8*)&Bs[(((((nh << 2) + j) << 1) | kh) * 64 + lane) * 8];
#pragma unroll
            for (int i = 0; i < 4; ++i)
#pragma unroll
                for (int j = 0; j < 4; ++j)
                    acc[i][j] = __builtin_amdgcn_mfma_f32_16x16x32_bf16(a[i], bb[j], acc[i][j], 0, 0, 0);
        }
    }

    const int col = lane & 15, rquad = lane >> 4;
#pragma unroll
    for (int i = 0; i < 4; ++i)
#pragma unroll
        for (int j = 0; j < 4; ++j)
#pragma unroll
            for (int r = 0; r < 4; ++r) {
                int gr = m0 + (mh << 6) + (i << 4) + (rquad << 2) + r;
                int gc = n0 + (nh << 6) + (j << 4) + col;
                if (gr < 680)
                    out[((size_t)b * 680 + gr) * 640 + gc] = acc[i][j][r];
            }
}

// ---------------------------------------------------------------------------
// Batched PV GEMM: mem[b][680][1024] = P_b[680x640] @ [sv ; vc_b].
// A = P bf16, row stride 1280 u16 (P lives in-place over the fp32 logits rows).
// B row c (output channel): k<320 -> svT_bf[c][320] ; k>=320 -> vcT_bf[b][c][k-320].
// K=640 (both halves in one pass -> no accumulate flag needed).
// ---------------------------------------------------------------------------
__global__ __launch_bounds__(256) void gemm_pv(
    const u16* __restrict__ P, const u16* __restrict__ svT,
    const u16* __restrict__ vcT, float* __restrict__ out)
{
    __shared__ __align__(16) u16 As[16 * 64 * 8];
    __shared__ __align__(16) u16 Bs[16 * 64 * 8];

    const int tid  = threadIdx.x;
    const int m0   = blockIdx.x << 7;
    const int n0   = blockIdx.y << 7;
    const int b    = blockIdx.z;
    const int wave = tid >> 6;
    const int lane = tid & 63;
    const int mh   = wave & 1;
    const int nh   = wave >> 1;

    floatx4 acc[4][4];
#pragma unroll
    for (int i = 0; i < 4; ++i)
#pragma unroll
        for (int j = 0; j < 4; ++j) acc[i][j] = (floatx4){0.f, 0.f, 0.f, 0.f};

    for (int k0 = 0; k0 < 640; k0 += 64) {
        __syncthreads();
#pragma unroll
        for (int p = 0; p < 4; ++p) {
            int q = tid + (p << 8);
            int row = q >> 3, cq = q & 7;
            int gr = m0 + row; if (gr > 679) gr = 679;
            *(uint4*)&As[((((row >> 4) << 1) | (cq >> 2)) * 64 + ((cq & 3) << 4) + (row & 15)) * 8]
                = *(const uint4*)(P + ((size_t)b * 680 + gr) * 1280 + k0 + (cq << 3));
        }
#pragma unroll
        for (int p = 0; p < 4; ++p) {
            int q = tid + (p << 8);
            int row = q >> 3, cq = q & 7;
            int gn = n0 + row;                    // < 1024 always
            const u16* src = (k0 < 320)
                ? (svT + (size_t)gn * 320 + k0)
                : (vcT + ((size_t)b * 1024 + gn) * 320 + (k0 - 320));
            *(uint4*)&Bs[((((row >> 4) << 1) | (cq >> 2)) * 64 + ((cq & 3) << 4) + (row & 15)) * 8]
                = *(const uint4*)(src + (cq << 3));
        }
        __syncthreads();
#pragma unroll
        for (int kh = 0; kh < 2; ++kh) {
            bf16x8 a[4], bb[4];
#pragma unroll
            for (int i = 0; i < 4; ++i)
                a[i] = *(const bf16x8*)&As[(((((mh << 2) + i) << 1) | kh) * 64 + lane) * 8];
#pragma unroll
            for (int j = 0; j < 4; ++j)
                bb[j] = *(const bf16x8*)&Bs[(((((nh << 2) + j) << 1) | kh) * 64 + lane) * 8];
#pragma unroll
            for (int i = 0; i < 4; ++i)
#pragma unroll
                for (int j = 0; j < 4; ++j)
                    acc[i][j] = __builtin_amdgcn_mfma_f32_16x16x32_bf16(a[i], bb[j], acc[i][j], 0, 0, 0);
        }
    }

    const int col = lane & 15, rquad = lane >> 4;
#pragma unroll
    for (int i = 0; i < 4; ++i)
#pragma unroll
        for (int j = 0; j < 4; ++j)
#pragma unroll
            for (int r = 0; r < 4; ++r) {
                int gr = m0 + (mh << 6) + (i << 4) + (rquad << 2) + r;
                int gc = n0 + (nh << 6) + (j << 4) + col;
                if (gr < 680)
                    out[((size_t)b * 680 + gr) * 1024 + gc] = acc[i][j][r];
            }
}

// ---------------------------------------------------------------------------
// Masked dual softmax, one wave per token row; folds alpha into P.
// Reads logits row [640] fp32, writes P row [640] bf16 IN PLACE over the
// first 1280 bytes of the same row (all reads complete before stores).
// Keys j >= NK(scale) get P=0 so the full-K PV GEMM is exact.
// ---------------------------------------------------------------------------
__global__ __launch_bounds__(256) void softmax_kernel(
    float* __restrict__ logits, const float* __restrict__ alpha,
    const float* __restrict__ log_temp)
{
    const int tid  = threadIdx.x;
    const int w    = tid >> 6;
    const int lane = tid & 63;
    const int b    = blockIdx.y;
    const int l    = (blockIdx.x << 2) + w;     // 680 = 170*4, exact

    const int se[10] = {1,5,14,30,55,91,155,255,424,680};
    int isc = 0;
#pragma unroll
    for (int k = 0; k < 9; ++k) if (l >= se[k]) isc = k + 1;
    const int NK = (isc + 1) << 5;

    float temp = __expf(log_temp[0]);
    temp = fminf(fmaxf(temp, 0.05f), 1.0f);
    const float Ksc = 0.03125f / temp;

    float* row = logits + ((size_t)b * 680 + l) * 640;

    float ls[5], lc[5];
#pragma unroll
    for (int u = 0; u < 5; ++u) {
        int j = lane + (u << 6);
        bool v = j < NK;
        ls[u] = v ? row[j]       : -1e30f;
        lc[u] = v ? row[320 + j] : -1e30f;
    }
    float mxs = -1e30f, mxc = -1e30f;
#pragma unroll
    for (int u = 0; u < 5; ++u) { mxs = fmaxf(mxs, ls[u]); mxc = fmaxf(mxc, lc[u]); }
#pragma unroll
    for (int k = 32; k >= 1; k >>= 1) {
        mxs = fmaxf(mxs, __shfl_xor(mxs, k));
        mxc = fmaxf(mxc, __shfl_xor(mxc, k));
    }
    float es[5], ec[5], ss = 0.f, sc = 0.f;
#pragma unroll
    for (int u = 0; u < 5; ++u) {
        int j = lane + (u << 6);
        bool v = j < NK;
        es[u] = v ? __expf((ls[u] - mxs) * Ksc) : 0.f;
        ec[u] = v ? __expf((lc[u] - mxc) * Ksc) : 0.f;
        ss += es[u]; sc += ec[u];
    }
#pragma unroll
    for (int k = 32; k >= 1; k >>= 1) {
        ss += __shfl_xor(ss, k);
        sc += __shfl_xor(sc, k);
    }
    const float al = alpha[b * LTOT + l];
    const float wS = (1.f - al) / ss;
    const float wC = al / sc;

    u16* po = (u16*)row;
#pragma unroll
    for (int u = 0; u < 5; ++u) {
        int j = lane + (u << 6);
        po[j]       = f2bf(es[u] * wS);
        po[320 + j] = f2bf(ec[u] * wC);
    }
}

// ---------------------------------------------------------------------------
// fp32 elementwise -> bf16 (n4 = element count / 4)
// ---------------------------------------------------------------------------
__global__ __launch_bounds__(256) void castbf(
    const float* __restrict__ in, u16* __restrict__ out, int n4)
{
    int i = blockIdx.x * 256 + threadIdx.x;
    const int stride = gridDim.x * 256;
    for (; i < n4; i += stride) {
        const float4 v = ((const float4*)in)[i];
        uint2 o;
        o.x = (unsigned)f2bf(v.x) | ((unsigned)f2bf(v.y) << 16);
        o.y = (unsigned)f2bf(v.z) | ((unsigned)f2bf(v.w) << 16);
        ((uint2*)out)[i] = o;
    }
}

// ---------------------------------------------------------------------------
// transpose + cast: out[Cc][R] bf16 = in[R][Cc]^T.
// grid MUST be (ceil(Cc/32), ceil(R/32)) — guarded for safety.
// ---------------------------------------------------------------------------
__global__ __launch_bounds__(256) void tcast(
    const float* __restrict__ in, u16* __restrict__ out, int R, int Cc)
{
    __shared__ float t[32][33];
    const int bx = blockIdx.x * 32;   // Cc
    const int by = blockIdx.y * 32;   // R
    const int x = threadIdx.x & 31;
    const int y0 = threadIdx.x >> 5;
#pragma unroll
    for (int yy = y0; yy < 32; yy += 8)
        t[yy][x] = (by + yy < R && bx + x < Cc)
                 ? in[(size_t)(by + yy) * Cc + bx + x] : 0.f;
    __syncthreads();
#pragma unroll
    for (int yy = y0; yy < 32; yy += 8)
        if (bx + yy < Cc && by + x < R)
            out[(size_t)(bx + yy) * R + by + x] = f2bf(t[x][yy]);
}

// ---------------------------------------------------------------------------
// 32x32 fp32 transpose, same grid convention, guarded.
// ---------------------------------------------------------------------------
__global__ __launch_bounds__(256) void transpose32(
    const float* __restrict__ in, float* __restrict__ out, int R, int Cc)
{
    __shared__ float t[32][33];
    const int bx = blockIdx.x * 32;
    const int by = blockIdx.y * 32;
    const int x = threadIdx.x & 31;
    const int y0 = threadIdx.x >> 5;
#pragma unroll
    for (int yy = y0; yy < 32; yy += 8)
        t[yy][x] = (by + yy < R && bx + x < Cc)
                 ? in[(size_t)(by + yy) * Cc + bx + x] : 0.f;
    __syncthreads();
#pragma unroll
    for (int yy = y0; yy < 32; yy += 8)
        if (bx + yy < Cc && by + x < R)
            out[(size_t)(bx + yy) * R + by + x] = t[x][yy];
}

// ---------------------------------------------------------------------------
// kc[b][j][c] bf16 = sk[j][c] + sum_r a[b,v,r] * catBK[(v*8+r)*32+slot][c]
// (row-major key layout: B-operand of the logits GEMM)
// ---------------------------------------------------------------------------
__global__ __launch_bounds__(256) void build_kc(
    const float* __restrict__ sk, const float* __restrict__ catBK,
    const float* __restrict__ cat_A, const int* __restrict__ cat_ids,
    u16* __restrict__ kc)
{
    const int b = blockIdx.x;
    const int jrow = blockIdx.y;
    const int v = jrow >> 5, slot = jrow & 31;
    int cid = cat_ids[b]; if (cid < 0) cid = 0;
    float a[8];
#pragma unroll
    for (int r = 0; r < 8; ++r) a[r] = cat_A[(cid * 10 + v) * 8 + r];
    const int c = threadIdx.x << 2;
    float4 acc = *(const float4*)(sk + (size_t)jrow * 1024 + c);
#pragma unroll
    for (int r = 0; r < 8; ++r) {
        const float4 bv = *(const float4*)(catBK + (size_t)((v * 8 + r) * 32 + slot) * 1024 + c);
        acc.x = fmaf(a[r], bv.x, acc.x);
        acc.y = fmaf(a[r], bv.y, acc.y);
        acc.z = fmaf(a[r], bv.z, acc.z);
        acc.w = fmaf(a[r], bv.w, acc.w);
    }
    uint2 pk;
    pk.x = (unsigned)f2bf(acc.x) | ((unsigned)f2bf(acc.y) << 16);
    pk.y = (unsigned)f2bf(acc.z) | ((unsigned)f2bf(acc.w) << 16);
    *(uint2*)(kc + ((size_t)b * 320 + jrow) * 1024 + c) = pk;
}

// ---------------------------------------------------------------------------
// vcT[b][c][j] bf16 = svT[c][j] + sum_r a[b,v,r] * catBVT[c][(v*8+r)*32+slot]
// (transposed value layout: B-operand of the PV GEMM)
// ---------------------------------------------------------------------------
__global__ __launch_bounds__(320) void build_vcT(
    const float* __restrict__ svT, const float* __restrict__ catBVT,
    const float* __restrict__ cat_A, const int* __restrict__ cat_ids,
    u16* __restrict__ vcT)
{
    __shared__ float aS[80];
    const int b = blockIdx.x;
    const int c = blockIdx.y;
    const int tid = threadIdx.x;
    if (tid < 80) {
        int cid = cat_ids[b]; if (cid < 0) cid = 0;
        aS[tid] = cat_A[cid * 80 + tid];
    }
    __syncthreads();
    const int j = tid;
    const int v = j >> 5, slot = j & 31;
    float acc = svT[(size_t)c * 320 + j];
    const float* row = catBVT + (size_t)c * 2560;
#pragma unroll
    for (int r = 0; r < 8; ++r)
        acc = fmaf(aS[v * 8 + r], row[(v * 8 + r) * 32 + slot], acc);
    vcT[((size_t)b * 1024 + c) * 320 + j] = f2bf(acc);
}

// ---------------------------------------------------------------------------
// bias2[b][i][j] = ce[b]@aW1[1024:2048,j] + scale_emb[i]@aW1[2048:3072,j] + ab1[j]
// ---------------------------------------------------------------------------
__global__ __launch_bounds__(128) void bias2_kernel(
    const float* __restrict__ cat_emb, const float* __restrict__ scale_emb,
    const float* __restrict__ aW1, const float* __restrict__ ab1,
    const int* __restrict__ cat_ids, float* __restrict__ bias2)
{
    const int b = blockIdx.x / 10;
    const int i = blockIdx.x - b * 10;
    const int j = threadIdx.x;
    int cid = cat_ids[b]; if (cid < 0) cid = 0;
    const float* ce = cat_emb + (size_t)cid * 1024;
    const float* se = scale_emb + (size_t)i * 1024;
    float acc = ab1[j];
    for (int c = 0; c < 1024; ++c) {
        acc = fmaf(ce[c], aW1[(size_t)(1024 + c) * 128 + j], acc);
        acc = fmaf(se[c], aW1[(size_t)(2048 + c) * 128 + j], acc);
    }
    bias2[(b * 10 + i) * 128 + j] = acc;
}

// ---------------------------------------------------------------------------
// alpha[b][l] = valid ? sigmoid( gelu(q@aW1_top + bias2[b,i]) @ aW2 + ab2 ) : 0
// query is bf16 now.
// ---------------------------------------------------------------------------
__global__ __launch_bounds__(128) void alpha_kernel(
    const u16* __restrict__ query, const float* __restrict__ aW1,
    const float* __restrict__ aW2, const float* __restrict__ ab2,
    const float* __restrict__ bias2, const int* __restrict__ cat_ids,
    float* __restrict__ alpha)
{
    __shared__ float qs[8][1024];
    __shared__ float red[8][128];
    const int tid = threadIdx.x;
    const int blk = blockIdx.x;
    const int b = blk / NCHUNK;
    const int chunk = blk - b * NCHUNK;
    int isc, l0, nq;
    chunk_info(chunk, &isc, &l0, &nq);
    const size_t qbase = ((size_t)b * LTOT + l0) * 1024;

    for (int idx = tid; idx < 8 * 128; idx += 128) {
        int t = idx >> 7;
        int c8 = (idx & 127) << 3;
        uint4 v = make_uint4(0u, 0u, 0u, 0u);
        if (t < nq) v = *(const uint4*)(query + qbase + (size_t)t * 1024 + c8);
        float4 lo, hi;
        lo.x = bf2f(v.x); lo.y = bf2f(v.x >> 16);
        lo.z = bf2f(v.y); lo.w = bf2f(v.y >> 16);
        hi.x = bf2f(v.z); hi.y = bf2f(v.z >> 16);
        hi.z = bf2f(v.w); hi.w = bf2f(v.w >> 16);
        *(float4*)&qs[t][c8]     = lo;
        *(float4*)&qs[t][c8 + 4] = hi;
    }
    __syncthreads();
    const int j = tid;
    float acc[8];
#pragma unroll
    for (int t = 0; t < 8; ++t) acc[t] = 0.f;
    for (int c = 0; c < 1024; ++c) {
        float w = aW1[(size_t)c * 128 + j];
#pragma unroll
        for (int t = 0; t < 8; ++t) acc[t] = fmaf(qs[t][c], w, acc[t]);
    }
    const float b2 = bias2[(b * 10 + isc) * 128 + j];
    const float w2 = aW2[j];
#pragma unroll
    for (int t = 0; t < 8; ++t) {
        float h = acc[t] + b2;
        h = 0.5f * h * (1.0f + erff(h * 0.70710678118654752f));
        red[t][j] = h * w2;
    }
    __syncthreads();
    if (tid < 8) {
        float s = 0.f;
        for (int jj = 0; jj < 128; ++jj) s += red[tid][jj];
        if (tid < nq) {
            float al = 0.f;
            if (cat_ids[b] >= 0) al = 1.f / (1.f + expf(-(s + ab2[0])));
            alpha[b * LTOT + l0 + tid] = al;
        }
    }
}

__global__ void tail_zero(float* p)
{
    if (threadIdx.x < 2) p[threadIdx.x] = 0.f;
}

// ---------------------------------------------------------------------------
extern "C" void kernel_launch(void* const* d_in, const int* in_sizes, int n_in,
                              void* d_out, int out_size, void* d_ws, size_t ws_size,
                              hipStream_t stream)
{
    (void)in_sizes; (void)n_in;
    const float* x         = (const float*)d_in[0];
    const int*   cat_ids   = (const int*)  d_in[1];
    const float* sm        = (const float*)d_in[2];
    const float* cat_A     = (const float*)d_in[3];
    const float* cat_B     = (const float*)d_in[4];
    const float* cat_emb   = (const float*)d_in[5];
    const float* scale_emb = (const float*)d_in[6];
    const float* Wq        = (const float*)d_in[7];
    const float* Wk        = (const float*)d_in[8];
    const float* Wv        = (const float*)d_in[9];
    const float* aW1       = (const float*)d_in[10];
    const float* ab1       = (const float*)d_in[11];
    const float* aW2       = (const float*)d_in[12];
    const float* ab2       = (const float*)d_in[13];
    const float* kW1       = (const float*)d_in[14];
    const float* kb1       = (const float*)d_in[15];
    const float* kW2       = (const float*)d_in[16];
    const float* kb2       = (const float*)d_in[17];
    const float* vW1       = (const float*)d_in[18];
    const float* vb1       = (const float*)d_in[19];
    const float* vW2       = (const float*)d_in[20];
    const float* vb2       = (const float*)d_in[21];
    const float* gk        = (const float*)d_in[22];
    const float* gv        = (const float*)d_in[23];
    const float* log_temp  = (const float*)d_in[24];

    float* out   = (float*)d_out;
    float* memb  = out;                          // mem, later overwritten by mem_k
    float* outv  = out + (size_t)21760 * 1024;   // mem_v region (hosts query_bf first)

    // ---- workspace layout (floats), total 25,785,600 f = 103.1 MB ----
    float* w      = (float*)d_ws;
    u16*   kc_bf  = (u16*)w;                     // [0, 5,242,880)  (10,485,760 u16)
    u16*   vcT_bf = (u16*)(w + 5242880);         // [5,242,880, 10,485,760)
    float* sk     = w + 10485760;                // 327,680
    float* sv     = w + 10813440;                // 327,680
    float* svT    = w + 11141120;                // 327,680
    u16*   sk_bf  = (u16*)(w + 11468800);        // 163,840 f-equiv
    u16*   svT_bf = (u16*)(w + 11632640);        // 163,840 f-equiv
    float* alph   = w + 11796480;                // 21,760
    float* bias2  = w + 11818240;                // 40,960
    float* logits = w + 11859200;                // 13,926,400  (ends 25,785,600)
    if (ws_size < (size_t)29881600 * 4) return;
    if (out_size < 2 * 21760 * 1024 + 2) return;

    // --- overlays (lifetime-disjoint with their hosts) ---
    // early scratch inside the logits region (dead before gemm_logits writes):
    u16*   x_bf   = (u16*)logits;                // 5,570,560 f-equiv
    float* bufA   = logits + 5570560;            // catBK  2,621,440
    float* bufB   = bufA + 2621440;              // catBV  2,621,440
    float* catBVT = bufB + 2621440;              // 2,621,440 (ends at logits+13,434,880)
    // projection weights inside the kc region (dead before build_kc writes):
    u16*   WqT    = (u16*)w;
    u16*   WkT    = WqT + 1048576;
    u16*   WvT    = WkT + 1048576;
    // small head weights inside sv (written after sv is consumed):
    u16*   kW1T   = (u16*)sv;
    u16*   vW1T   = kW1T + 65536;
    u16*   kW2T   = vW1T + 65536;
    u16*   vW2T   = kW2T + 65536;
    // final-projection intermediates over kc/vcT regions (dead after PV gemm):
    float* bufA2  = w;                           // 1,392,640 <= kc region
    float* bufB2  = w + 5242880;                 // 1,392,640 <= vcT region
    // query bf16 lives in out's second half; dead before the final mem_v gemm.
    u16*   query_bf = (u16*)outv;                // 11,141,120 f-equiv <= 22,282,240 f

    const dim3 blk256(256);

    // 0. casts / weight transposes (tcast grid = (Cc/32, R/32))
    castbf<<<dim3(2048), blk256, 0, stream>>>(x, x_bf, 21760 * 1024 / 4);
    tcast<<<dim3(32, 32), blk256, 0, stream>>>(Wq, WqT, 1024, 1024);
    tcast<<<dim3(32, 32), blk256, 0, stream>>>(Wk, WkT, 1024, 1024);
    tcast<<<dim3(32, 32), blk256, 0, stream>>>(Wv, WvT, 1024, 1024);

    // 1. projections (MFMA); query written directly as bf16
    gemm_mfma<0,1><<<dim3(170, 8), blk256, 0, stream>>>(x_bf, WqT, (float*)query_bf, 21760, 1024, 1024, nullptr, nullptr);
    gemm_mfma<1,0><<<dim3(3, 8),   blk256, 0, stream>>>(sm,   WkT, sk,   320,  1024, 1024, nullptr, nullptr);
    gemm_mfma<1,0><<<dim3(3, 8),   blk256, 0, stream>>>(sm,   WvT, sv,   320,  1024, 1024, nullptr, nullptr);
    gemm_mfma<1,0><<<dim3(20, 8),  blk256, 0, stream>>>(cat_B, WkT, bufA, 2560, 1024, 1024, nullptr, nullptr);
    gemm_mfma<1,0><<<dim3(20, 8),  blk256, 0, stream>>>(cat_B, WvT, bufB, 2560, 1024, 1024, nullptr, nullptr);

    // 2. derived key/value layouts
    castbf<<<dim3(320), blk256, 0, stream>>>(sk, sk_bf, 320 * 1024 / 4);
    transpose32<<<dim3(32, 10), blk256, 0, stream>>>(sv, svT, 320, 1024);
    tcast<<<dim3(32, 10), blk256, 0, stream>>>(sv, svT_bf, 320, 1024);
    transpose32<<<dim3(32, 80), blk256, 0, stream>>>(bufB, catBVT, 2560, 1024);
    // small head-weight transposes AFTER sv is consumed (they overlay sv)
    tcast<<<dim3(2, 32), blk256, 0, stream>>>(kW1, kW1T, 1024, 64);
    tcast<<<dim3(2, 32), blk256, 0, stream>>>(vW1, vW1T, 1024, 64);
    tcast<<<dim3(32, 2), blk256, 0, stream>>>(kW2, kW2T, 64, 1024);
    tcast<<<dim3(32, 2), blk256, 0, stream>>>(vW2, vW2T, 64, 1024);

    // 3. per-batch low-rank expanded K (row-major bf16) / V (transposed bf16)
    build_kc<<<dim3(NB, 320), blk256, 0, stream>>>(sk, bufA, cat_A, cat_ids, kc_bf);
    build_vcT<<<dim3(NB, 1024), dim3(320), 0, stream>>>(svT, catBVT, cat_A, cat_ids, vcT_bf);

    // 4. alpha gate
    bias2_kernel<<<dim3(NB * 10), dim3(128), 0, stream>>>(cat_emb, scale_emb, aW1, ab1, cat_ids, bias2);
    alpha_kernel<<<dim3(NB * NCHUNK), dim3(128), 0, stream>>>(query_bf, aW1, aW2, ab2, bias2, cat_ids, alph);

    // 5. attention as MFMA GEMMs: logits -> masked softmax (P in-place) -> PV
    gemm_logits<<<dim3(6, 5, NB), blk256, 0, stream>>>(query_bf, sk_bf, kc_bf, logits);
    softmax_kernel<<<dim3(170, NB), blk256, 0, stream>>>(logits, alph, log_temp);
    gemm_pv<<<dim3(6, 8, NB), blk256, 0, stream>>>((const u16*)logits, svT_bf, vcT_bf, memb);

    // 6. final low-rank projections (MFMA, inline-cast fp32 A)
    gemm_mfma<1,0><<<dim3(170, 1), blk256, 0, stream>>>(memb, kW1T, bufA2, 21760, 64, 1024, kb1, nullptr);
    gemm_mfma<1,0><<<dim3(170, 1), blk256, 0, stream>>>(memb, vW1T, bufB2, 21760, 64, 1024, vb1, nullptr);
    gemm_mfma<1,0><<<dim3(170, 8), blk256, 0, stream>>>(bufA2, kW2T, memb, 21760, 1024, 64, kb2, gk);
    gemm_mfma<1,0><<<dim3(170, 8), blk256, 0, stream>>>(bufB2, vW2T, outv, 21760, 1024, 64, vb2, gv);

    tail_zero<<<1, 64, 0, stream>>>(out + (size_t)2 * 21760 * 1024);
}

// Round 2
// 1100.704 us; speedup vs baseline: 1.9556x; 1.1425x over previous
//
#include <hip/hip_runtime.h>
#include <math.h>

// Problem constants
#define NB 32          // batch
#define NC 1024        // channels
#define LTOT 680       // total tokens per batch

typedef unsigned short u16;
typedef __bf16 bf16x8 __attribute__((ext_vector_type(8)));
typedef float floatx4 __attribute__((ext_vector_type(4)));

__device__ __forceinline__ u16 f2bf(float f)
{
    union { float f; unsigned u; } v; v.f = f;
    unsigned u = v.u;
    u += 0x7FFFu + ((u >> 16) & 1u);   // RNE
    return (u16)(u >> 16);
}

__device__ __forceinline__ float bf2f(unsigned u)
{
    union { unsigned u; float f; } v; v.u = u << 16; return v.f;
}

// ---------------------------------------------------------------------------
// bf16 MFMA GEMM (m97-style): C[MxN] fp32 = A[MxK] @ B, with B given as
// BT[NxK] bf16 row-major. 128x128 tile, BK=64, 256 threads = 4 waves in a
// 2x2 wave grid; each wave computes 4x4 frags of 16x16 (64x64 quadrant).
// LDS holds A/B tiles in FRAGMENT ORDER: [tile*2+kh][lane][8 bf16] so every
// ds_read/ds_write is lane-linear b128 (conflict-free).
// AFP32=1: A is fp32, cast to bf16 inline during staging.
// OUTBF=1: C stored as bf16 (u16) instead of fp32.
// lda = element stride between A rows (normally K).
// M,N arbitrary (clamped loads, guarded stores); K multiple of 64.
// ---------------------------------------------------------------------------
template<int AFP32, int OUTBF>
__global__ __launch_bounds__(256) void gemm_mfma(
    const void* __restrict__ Av, const u16* __restrict__ BT,
    float* __restrict__ C, int M, int N, int K, int lda,
    const float* __restrict__ bias, const float* __restrict__ scale_logit)
{
    __shared__ __align__(16) u16 As[16 * 64 * 8];   // 16KB
    __shared__ __align__(16) u16 Bs[16 * 64 * 8];   // 16KB

    const int tid  = threadIdx.x;
    const int m0   = blockIdx.x << 7;
    const int n0   = blockIdx.y << 7;
    const int wave = tid >> 6;
    const int lane = tid & 63;
    const int mh   = wave & 1;
    const int nh   = wave >> 1;

    floatx4 acc[4][4];
#pragma unroll
    for (int i = 0; i < 4; ++i)
#pragma unroll
        for (int j = 0; j < 4; ++j) acc[i][j] = (floatx4){0.f, 0.f, 0.f, 0.f};

    for (int k0 = 0; k0 < K; k0 += 64) {
        __syncthreads();
        // ---- stage A tile (128 rows x 64 k) into frag order ----
        if (AFP32) {
            const float* A = (const float*)Av;
#pragma unroll
            for (int p = 0; p < 8; ++p) {
                int q   = tid + (p << 8);          // 2048 chunks of 4 floats
                int row = q >> 4;
                int fq  = q & 15;                  // 4-float chunk within row
                int gr  = m0 + row; if (gr > M - 1) gr = M - 1;
                const float4 a4 = *(const float4*)(A + (size_t)gr * lda + k0 + (fq << 2));
                int kh = fq >> 3, quad = (fq >> 1) & 3, jh = fq & 1;
                u16* d = &As[((((row >> 4) << 1) | kh) * 64 + (quad << 4) + (row & 15)) * 8 + (jh << 2)];
                d[0] = f2bf(a4.x); d[1] = f2bf(a4.y); d[2] = f2bf(a4.z); d[3] = f2bf(a4.w);
            }
        } else {
            const u16* A = (const u16*)Av;
#pragma unroll
            for (int p = 0; p < 4; ++p) {
                int q   = tid + (p << 8);          // 1024 chunks of 8 bf16
                int row = q >> 3;
                int cq  = q & 7;
                int gr  = m0 + row; if (gr > M - 1) gr = M - 1;
                *(uint4*)&As[((((row >> 4) << 1) | (cq >> 2)) * 64 + ((cq & 3) << 4) + (row & 15)) * 8]
                    = *(const uint4*)(A + (size_t)gr * lda + k0 + (cq << 3));
            }
        }
        // ---- stage B tile (BT rows = output cols) ----
#pragma unroll
        for (int p = 0; p < 4; ++p) {
            int q   = tid + (p << 8);
            int row = q >> 3;
            int cq  = q & 7;
            int gn  = n0 + row; if (gn > N - 1) gn = N - 1;
            *(uint4*)&Bs[((((row >> 4) << 1) | (cq >> 2)) * 64 + ((cq & 3) << 4) + (row & 15)) * 8]
                = *(const uint4*)(BT + (size_t)gn * K + k0 + (cq << 3));
        }
        __syncthreads();
        // ---- MFMA over the two K-halves ----
#pragma unroll
        for (int kh = 0; kh < 2; ++kh) {
            bf16x8 a[4], b[4];
#pragma unroll
            for (int i = 0; i < 4; ++i)
                a[i] = *(const bf16x8*)&As[(((((mh << 2) + i) << 1) | kh) * 64 + lane) * 8];
#pragma unroll
            for (int j = 0; j < 4; ++j)
                b[j] = *(const bf16x8*)&Bs[(((((nh << 2) + j) << 1) | kh) * 64 + lane) * 8];
#pragma unroll
            for (int i = 0; i < 4; ++i)
#pragma unroll
                for (int j = 0; j < 4; ++j)
                    acc[i][j] = __builtin_amdgcn_mfma_f32_16x16x32_bf16(a[i], b[j], acc[i][j], 0, 0, 0);
        }
    }

    float scale = 1.f;
    if (scale_logit) scale = 1.f / (1.f + __expf(-scale_logit[0]));
    const int col = lane & 15, rquad = lane >> 4;
#pragma unroll
    for (int i = 0; i < 4; ++i) {
#pragma unroll
        for (int j = 0; j < 4; ++j) {
#pragma unroll
            for (int r = 0; r < 4; ++r) {
                int gr = m0 + (mh << 6) + (i << 4) + (rquad << 2) + r;
                int gc = n0 + (nh << 6) + (j << 4) + col;
                if (gr < M && gc < N) {
                    float bb = bias ? bias[gc] : 0.f;
                    float val = scale * (acc[i][j][r] + bb);
                    if (OUTBF) ((u16*)C)[(size_t)gr * N + gc] = f2bf(val);
                    else       C[(size_t)gr * N + gc] = val;
                }
            }
        }
    }
}

// ---------------------------------------------------------------------------
// Batched logits GEMM: out[b][680][640] = Q_b[680x1024] @ [sk ; kc_b]^T.
// ---------------------------------------------------------------------------
__global__ __launch_bounds__(256) void gemm_logits(
    const u16* __restrict__ Q, const u16* __restrict__ skb,
    const u16* __restrict__ kcb, float* __restrict__ out)
{
    __shared__ __align__(16) u16 As[16 * 64 * 8];
    __shared__ __align__(16) u16 Bs[16 * 64 * 8];

    const int tid  = threadIdx.x;
    const int m0   = blockIdx.x << 7;
    const int n0   = blockIdx.y << 7;
    const int b    = blockIdx.z;
    const int wave = tid >> 6;
    const int lane = tid & 63;
    const int mh   = wave & 1;
    const int nh   = wave >> 1;

    const u16* Ab = Q   + (size_t)b * 680 * 1024;
    const u16* KC = kcb + (size_t)b * 320 * 1024;

    floatx4 acc[4][4];
#pragma unroll
    for (int i = 0; i < 4; ++i)
#pragma unroll
        for (int j = 0; j < 4; ++j) acc[i][j] = (floatx4){0.f, 0.f, 0.f, 0.f};

    for (int k0 = 0; k0 < 1024; k0 += 64) {
        __syncthreads();
#pragma unroll
        for (int p = 0; p < 4; ++p) {
            int q = tid + (p << 8);
            int row = q >> 3, cq = q & 7;
            int gr = m0 + row; if (gr > 679) gr = 679;
            *(uint4*)&As[((((row >> 4) << 1) | (cq >> 2)) * 64 + ((cq & 3) << 4) + (row & 15)) * 8]
                = *(const uint4*)(Ab + (size_t)gr * 1024 + k0 + (cq << 3));
        }
#pragma unroll
        for (int p = 0; p < 4; ++p) {
            int q = tid + (p << 8);
            int row = q >> 3, cq = q & 7;
            int gn = n0 + row;                    // < 640 always
            const u16* src = (gn < 320) ? (skb + (size_t)gn * 1024)
                                        : (KC + (size_t)(gn - 320) * 1024);
            *(uint4*)&Bs[((((row >> 4) << 1) | (cq >> 2)) * 64 + ((cq & 3) << 4) + (row & 15)) * 8]
                = *(const uint4*)(src + k0 + (cq << 3));
        }
        __syncthreads();
#pragma unroll
        for (int kh = 0; kh < 2; ++kh) {
            bf16x8 a[4], bb[4];
#pragma unroll
            for (int i = 0; i < 4; ++i)
                a[i] = *(const bf16x8*)&As[(((((mh << 2) + i) << 1) | kh) * 64 + lane) * 8];
#pragma unroll
            for (int j = 0; j < 4; ++j)
                bb[j] = *(const bf16x8*)&Bs[(((((nh << 2) + j) << 1) | kh) * 64 + lane) * 8];
#pragma unroll
            for (int i = 0; i < 4; ++i)
#pragma unroll
                for (int j = 0; j < 4; ++j)
                    acc[i][j] = __builtin_amdgcn_mfma_f32_16x16x32_bf16(a[i], bb[j], acc[i][j], 0, 0, 0);
        }
    }

    const int col = lane & 15, rquad = lane >> 4;
#pragma unroll
    for (int i = 0; i < 4; ++i)
#pragma unroll
        for (int j = 0; j < 4; ++j)
#pragma unroll
            for (int r = 0; r < 4; ++r) {
                int gr = m0 + (mh << 6) + (i << 4) + (rquad << 2) + r;
                int gc = n0 + (nh << 6) + (j << 4) + col;
                if (gr < 680)
                    out[((size_t)b * 680 + gr) * 640 + gc] = acc[i][j][r];
            }
}

// ---------------------------------------------------------------------------
// Batched PV GEMM: mem[b][680][1024] = P_b[680x640] @ [sv ; vc_b].
// A = P bf16, row stride 1280 u16 (P lives in-place over the fp32 logits rows).
// ---------------------------------------------------------------------------
__global__ __launch_bounds__(256) void gemm_pv(
    const u16* __restrict__ P, const u16* __restrict__ svT,
    const u16* __restrict__ vcT, float* __restrict__ out)
{
    __shared__ __align__(16) u16 As[16 * 64 * 8];
    __shared__ __align__(16) u16 Bs[16 * 64 * 8];

    const int tid  = threadIdx.x;
    const int m0   = blockIdx.x << 7;
    const int n0   = blockIdx.y << 7;
    const int b    = blockIdx.z;
    const int wave = tid >> 6;
    const int lane = tid & 63;
    const int mh   = wave & 1;
    const int nh   = wave >> 1;

    floatx4 acc[4][4];
#pragma unroll
    for (int i = 0; i < 4; ++i)
#pragma unroll
        for (int j = 0; j < 4; ++j) acc[i][j] = (floatx4){0.f, 0.f, 0.f, 0.f};

    for (int k0 = 0; k0 < 640; k0 += 64) {
        __syncthreads();
#pragma unroll
        for (int p = 0; p < 4; ++p) {
            int q = tid + (p << 8);
            int row = q >> 3, cq = q & 7;
            int gr = m0 + row; if (gr > 679) gr = 679;
            *(uint4*)&As[((((row >> 4) << 1) | (cq >> 2)) * 64 + ((cq & 3) << 4) + (row & 15)) * 8]
                = *(const uint4*)(P + ((size_t)b * 680 + gr) * 1280 + k0 + (cq << 3));
        }
#pragma unroll
        for (int p = 0; p < 4; ++p) {
            int q = tid + (p << 8);
            int row = q >> 3, cq = q & 7;
            int gn = n0 + row;                    // < 1024 always
            const u16* src = (k0 < 320)
                ? (svT + (size_t)gn * 320 + k0)
                : (vcT + ((size_t)b * 1024 + gn) * 320 + (k0 - 320));
            *(uint4*)&Bs[((((row >> 4) << 1) | (cq >> 2)) * 64 + ((cq & 3) << 4) + (row & 15)) * 8]
                = *(const uint4*)(src + (cq << 3));
        }
        __syncthreads();
#pragma unroll
        for (int kh = 0; kh < 2; ++kh) {
            bf16x8 a[4], bb[4];
#pragma unroll
            for (int i = 0; i < 4; ++i)
                a[i] = *(const bf16x8*)&As[(((((mh << 2) + i) << 1) | kh) * 64 + lane) * 8];
#pragma unroll
            for (int j = 0; j < 4; ++j)
                bb[j] = *(const bf16x8*)&Bs[(((((nh << 2) + j) << 1) | kh) * 64 + lane) * 8];
#pragma unroll
            for (int i = 0; i < 4; ++i)
#pragma unroll
                for (int j = 0; j < 4; ++j)
                    acc[i][j] = __builtin_amdgcn_mfma_f32_16x16x32_bf16(a[i], bb[j], acc[i][j], 0, 0, 0);
        }
    }

    const int col = lane & 15, rquad = lane >> 4;
#pragma unroll
    for (int i = 0; i < 4; ++i)
#pragma unroll
        for (int j = 0; j < 4; ++j)
#pragma unroll
            for (int r = 0; r < 4; ++r) {
                int gr = m0 + (mh << 6) + (i << 4) + (rquad << 2) + r;
                int gc = n0 + (nh << 6) + (j << 4) + col;
                if (gr < 680)
                    out[((size_t)b * 680 + gr) * 1024 + gc] = acc[i][j][r];
            }
}

// ---------------------------------------------------------------------------
// Alpha hidden GEMM: h[21760][128] bf16 = gelu( Q @ aW1_topT
//                     + ceW[cid[b]] + seW[isc(l)] )   (seW includes ab1)
// M=21760, N=128, K=1024 fixed; grid (170,1).
// ---------------------------------------------------------------------------
__global__ __launch_bounds__(256) void gemm_halpha(
    const u16* __restrict__ Q, const u16* __restrict__ W,
    const float* __restrict__ ceW, const float* __restrict__ seW,
    const int* __restrict__ cat_ids, u16* __restrict__ h)
{
    __shared__ __align__(16) u16 As[16 * 64 * 8];
    __shared__ __align__(16) u16 Bs[16 * 64 * 8];

    const int tid  = threadIdx.x;
    const int m0   = blockIdx.x << 7;
    const int wave = tid >> 6;
    const int lane = tid & 63;
    const int mh   = wave & 1;
    const int nh   = wave >> 1;

    floatx4 acc[4][4];
#pragma unroll
    for (int i = 0; i < 4; ++i)
#pragma unroll
        for (int j = 0; j < 4; ++j) acc[i][j] = (floatx4){0.f, 0.f, 0.f, 0.f};

    for (int k0 = 0; k0 < 1024; k0 += 64) {
        __syncthreads();
#pragma unroll
        for (int p = 0; p < 4; ++p) {
            int q = tid + (p << 8);
            int row = q >> 3, cq = q & 7;
            int gr = m0 + row;                     // < 21760 always (170*128)
            *(uint4*)&As[((((row >> 4) << 1) | (cq >> 2)) * 64 + ((cq & 3) << 4) + (row & 15)) * 8]
                = *(const uint4*)(Q + (size_t)gr * 1024 + k0 + (cq << 3));
        }
#pragma unroll
        for (int p = 0; p < 4; ++p) {
            int q = tid + (p << 8);
            int row = q >> 3, cq = q & 7;          // row < 128 = N exactly
            *(uint4*)&Bs[((((row >> 4) << 1) | (cq >> 2)) * 64 + ((cq & 3) << 4) + (row & 15)) * 8]
                = *(const uint4*)(W + (size_t)row * 1024 + k0 + (cq << 3));
        }
        __syncthreads();
#pragma unroll
        for (int kh = 0; kh < 2; ++kh) {
            bf16x8 a[4], bb[4];
#pragma unroll
            for (int i = 0; i < 4; ++i)
                a[i] = *(const bf16x8*)&As[(((((mh << 2) + i) << 1) | kh) * 64 + lane) * 8];
#pragma unroll
            for (int j = 0; j < 4; ++j)
                bb[j] = *(const bf16x8*)&Bs[(((((nh << 2) + j) << 1) | kh) * 64 + lane) * 8];
#pragma unroll
            for (int i = 0; i < 4; ++i)
#pragma unroll
                for (int j = 0; j < 4; ++j)
                    acc[i][j] = __builtin_amdgcn_mfma_f32_16x16x32_bf16(a[i], bb[j], acc[i][j], 0, 0, 0);
        }
    }

    const int se_[9] = {1,5,14,30,55,91,155,255,424};
    const int col = lane & 15, rquad = lane >> 4;
#pragma unroll
    for (int i = 0; i < 4; ++i) {
#pragma unroll
        for (int r = 0; r < 4; ++r) {
            int gr = m0 + (mh << 6) + (i << 4) + (rquad << 2) + r;
            int b  = gr / 680;
            int l  = gr - b * 680;
            int isc = 0;
#pragma unroll
            for (int k = 0; k < 9; ++k) if (l >= se_[k]) isc = k + 1;
            int cid = cat_ids[b]; if (cid < 0) cid = 0;
            const float* cw = ceW + cid * 128;
            const float* sw = seW + isc * 128;
#pragma unroll
            for (int j = 0; j < 4; ++j) {
                int gc = (nh << 6) + (j << 4) + col;
                float val = acc[i][j][r] + cw[gc] + sw[gc];
                float g = 0.5f * val * (1.0f + erff(val * 0.70710678118654752f));
                h[(size_t)gr * 128 + gc] = f2bf(g);
            }
        }
    }
}

// ---------------------------------------------------------------------------
// alpha[row] = valid ? sigmoid( dot(h[row], aW2) + ab2 ) : 0.
// One wave per row; grid 21760/4 blocks of 256.
// ---------------------------------------------------------------------------
__global__ __launch_bounds__(256) void alpha_reduce(
    const u16* __restrict__ h, const float* __restrict__ aW2,
    const float* __restrict__ ab2, const int* __restrict__ cat_ids,
    float* __restrict__ alpha)
{
    const int wave = threadIdx.x >> 6;
    const int lane = threadIdx.x & 63;
    const int row  = (blockIdx.x << 2) + wave;   // < 21760 exact

    const unsigned pk = *(const unsigned*)(h + (size_t)row * 128 + (lane << 1));
    float s = bf2f(pk) * aW2[lane << 1] + bf2f(pk >> 16) * aW2[(lane << 1) + 1];
#pragma unroll
    for (int k = 32; k >= 1; k >>= 1) s += __shfl_xor(s, k);
    if (lane == 0) {
        int b = row / 680;
        float al = 0.f;
        if (cat_ids[b] >= 0) al = 1.f / (1.f + expf(-(s + ab2[0])));
        alpha[row] = al;
    }
}

// ---------------------------------------------------------------------------
// Masked dual softmax, one wave per token row; folds alpha into P.
// Reads logits row [640] fp32, writes P row [640] bf16 IN PLACE over the
// first 1280 bytes of the same row (all reads complete before stores).
// ---------------------------------------------------------------------------
__global__ __launch_bounds__(256) void softmax_kernel(
    float* __restrict__ logits, const float* __restrict__ alpha,
    const float* __restrict__ log_temp)
{
    const int tid  = threadIdx.x;
    const int w    = tid >> 6;
    const int lane = tid & 63;
    const int b    = blockIdx.y;
    const int l    = (blockIdx.x << 2) + w;     // 680 = 170*4, exact

    const int se[10] = {1,5,14,30,55,91,155,255,424,680};
    int isc = 0;
#pragma unroll
    for (int k = 0; k < 9; ++k) if (l >= se[k]) isc = k + 1;
    const int NK = (isc + 1) << 5;

    float temp = __expf(log_temp[0]);
    temp = fminf(fmaxf(temp, 0.05f), 1.0f);
    const float Ksc = 0.03125f / temp;

    float* row = logits + ((size_t)b * 680 + l) * 640;

    float ls[5], lc[5];
#pragma unroll
    for (int u = 0; u < 5; ++u) {
        int j = lane + (u << 6);
        bool v = j < NK;
        ls[u] = v ? row[j]       : -1e30f;
        lc[u] = v ? row[320 + j] : -1e30f;
    }
    float mxs = -1e30f, mxc = -1e30f;
#pragma unroll
    for (int u = 0; u < 5; ++u) { mxs = fmaxf(mxs, ls[u]); mxc = fmaxf(mxc, lc[u]); }
#pragma unroll
    for (int k = 32; k >= 1; k >>= 1) {
        mxs = fmaxf(mxs, __shfl_xor(mxs, k));
        mxc = fmaxf(mxc, __shfl_xor(mxc, k));
    }
    float es[5], ec[5], ss = 0.f, sc = 0.f;
#pragma unroll
    for (int u = 0; u < 5; ++u) {
        int j = lane + (u << 6);
        bool v = j < NK;
        es[u] = v ? __expf((ls[u] - mxs) * Ksc) : 0.f;
        ec[u] = v ? __expf((lc[u] - mxc) * Ksc) : 0.f;
        ss += es[u]; sc += ec[u];
    }
#pragma unroll
    for (int k = 32; k >= 1; k >>= 1) {
        ss += __shfl_xor(ss, k);
        sc += __shfl_xor(sc, k);
    }
    const float al = alpha[b * LTOT + l];
    const float wS = (1.f - al) / ss;
    const float wC = al / sc;

    u16* po = (u16*)row;
#pragma unroll
    for (int u = 0; u < 5; ++u) {
        int j = lane + (u << 6);
        po[j]       = f2bf(es[u] * wS);
        po[320 + j] = f2bf(ec[u] * wC);
    }
}

// ---------------------------------------------------------------------------
// fp32 elementwise -> bf16 (n4 = element count / 4)
// ---------------------------------------------------------------------------
__global__ __launch_bounds__(256) void castbf(
    const float* __restrict__ in, u16* __restrict__ out, int n4)
{
    int i = blockIdx.x * 256 + threadIdx.x;
    const int stride = gridDim.x * 256;
    for (; i < n4; i += stride) {
        const float4 v = ((const float4*)in)[i];
        uint2 o;
        o.x = (unsigned)f2bf(v.x) | ((unsigned)f2bf(v.y) << 16);
        o.y = (unsigned)f2bf(v.z) | ((unsigned)f2bf(v.w) << 16);
        ((uint2*)out)[i] = o;
    }
}

// ---------------------------------------------------------------------------
// transpose + cast: out[Cc][R] bf16 = in[R][Cc]^T.
// grid MUST be (ceil(Cc/32), ceil(R/32)) — guarded for safety.
// ---------------------------------------------------------------------------
__global__ __launch_bounds__(256) void tcast(
    const float* __restrict__ in, u16* __restrict__ out, int R, int Cc)
{
    __shared__ float t[32][33];
    const int bx = blockIdx.x * 32;   // Cc
    const int by = blockIdx.y * 32;   // R
    const int x = threadIdx.x & 31;
    const int y0 = threadIdx.x >> 5;
#pragma unroll
    for (int yy = y0; yy < 32; yy += 8)
        t[yy][x] = (by + yy < R && bx + x < Cc)
                 ? in[(size_t)(by + yy) * Cc + bx + x] : 0.f;
    __syncthreads();
#pragma unroll
    for (int yy = y0; yy < 32; yy += 8)
        if (bx + yy < Cc && by + x < R)
            out[(size_t)(bx + yy) * R + by + x] = f2bf(t[x][yy]);
}

// ---------------------------------------------------------------------------
// 32x32 fp32 transpose, same grid convention, guarded.
// ---------------------------------------------------------------------------
__global__ __launch_bounds__(256) void transpose32(
    const float* __restrict__ in, float* __restrict__ out, int R, int Cc)
{
    __shared__ float t[32][33];
    const int bx = blockIdx.x * 32;
    const int by = blockIdx.y * 32;
    const int x = threadIdx.x & 31;
    const int y0 = threadIdx.x >> 5;
#pragma unroll
    for (int yy = y0; yy < 32; yy += 8)
        t[yy][x] = (by + yy < R && bx + x < Cc)
                 ? in[(size_t)(by + yy) * Cc + bx + x] : 0.f;
    __syncthreads();
#pragma unroll
    for (int yy = y0; yy < 32; yy += 8)
        if (bx + yy < Cc && by + x < R)
            out[(size_t)(bx + yy) * R + by + x] = t[x][yy];
}

// ---------------------------------------------------------------------------
// kc[b][j][c] bf16 = sk[j][c] + sum_r a[b,v,r] * catBK[(v*8+r)*32+slot][c]
// ---------------------------------------------------------------------------
__global__ __launch_bounds__(256) void build_kc(
    const float* __restrict__ sk, const float* __restrict__ catBK,
    const float* __restrict__ cat_A, const int* __restrict__ cat_ids,
    u16* __restrict__ kc)
{
    const int b = blockIdx.x;
    const int jrow = blockIdx.y;
    const int v = jrow >> 5, slot = jrow & 31;
    int cid = cat_ids[b]; if (cid < 0) cid = 0;
    float a[8];
#pragma unroll
    for (int r = 0; r < 8; ++r) a[r] = cat_A[(cid * 10 + v) * 8 + r];
    const int c = threadIdx.x << 2;
    float4 acc = *(const float4*)(sk + (size_t)jrow * 1024 + c);
#pragma unroll
    for (int r = 0; r < 8; ++r) {
        const float4 bv = *(const float4*)(catBK + (size_t)((v * 8 + r) * 32 + slot) * 1024 + c);
        acc.x = fmaf(a[r], bv.x, acc.x);
        acc.y = fmaf(a[r], bv.y, acc.y);
        acc.z = fmaf(a[r], bv.z, acc.z);
        acc.w = fmaf(a[r], bv.w, acc.w);
    }
    uint2 pk;
    pk.x = (unsigned)f2bf(acc.x) | ((unsigned)f2bf(acc.y) << 16);
    pk.y = (unsigned)f2bf(acc.z) | ((unsigned)f2bf(acc.w) << 16);
    *(uint2*)(kc + ((size_t)b * 320 + jrow) * 1024 + c) = pk;
}

// ---------------------------------------------------------------------------
// vcT[b][c][j] bf16 = svT[c][j] + sum_r a[b,v,r] * catBVT[c][(v*8+r)*32+slot]
// ---------------------------------------------------------------------------
__global__ __launch_bounds__(320) void build_vcT(
    const float* __restrict__ svT, const float* __restrict__ catBVT,
    const float* __restrict__ cat_A, const int* __restrict__ cat_ids,
    u16* __restrict__ vcT)
{
    __shared__ float aS[80];
    const int b = blockIdx.x;
    const int c = blockIdx.y;
    const int tid = threadIdx.x;
    if (tid < 80) {
        int cid = cat_ids[b]; if (cid < 0) cid = 0;
        aS[tid] = cat_A[cid * 80 + tid];
    }
    __syncthreads();
    const int j = tid;
    const int v = j >> 5, slot = j & 31;
    float acc = svT[(size_t)c * 320 + j];
    const float* row = catBVT + (size_t)c * 2560;
#pragma unroll
    for (int r = 0; r < 8; ++r)
        acc = fmaf(aS[v * 8 + r], row[(v * 8 + r) * 32 + slot], acc);
    vcT[((size_t)b * 1024 + c) * 320 + j] = f2bf(acc);
}

// ---------------------------------------------------------------------------
// cb[0:64] = kb1, cb[64:128] = vb1
// ---------------------------------------------------------------------------
__global__ void concat_bias(const float* __restrict__ a,
                            const float* __restrict__ b, float* __restrict__ o)
{
    int t = threadIdx.x;
    if (t < 64) o[t] = a[t];
    else if (t < 128) o[t] = b[t - 64];
}

__global__ void tail_zero(float* p)
{
    if (threadIdx.x < 2) p[threadIdx.x] = 0.f;
}

// ---------------------------------------------------------------------------
extern "C" void kernel_launch(void* const* d_in, const int* in_sizes, int n_in,
                              void* d_out, int out_size, void* d_ws, size_t ws_size,
                              hipStream_t stream)
{
    (void)in_sizes; (void)n_in;
    const float* x         = (const float*)d_in[0];
    const int*   cat_ids   = (const int*)  d_in[1];
    const float* sm        = (const float*)d_in[2];
    const float* cat_A     = (const float*)d_in[3];
    const float* cat_B     = (const float*)d_in[4];
    const float* cat_emb   = (const float*)d_in[5];
    const float* scale_emb = (const float*)d_in[6];
    const float* Wq        = (const float*)d_in[7];
    const float* Wk        = (const float*)d_in[8];
    const float* Wv        = (const float*)d_in[9];
    const float* aW1       = (const float*)d_in[10];
    const float* ab1       = (const float*)d_in[11];
    const float* aW2       = (const float*)d_in[12];
    const float* ab2       = (const float*)d_in[13];
    const float* kW1       = (const float*)d_in[14];
    const float* kb1       = (const float*)d_in[15];
    const float* kW2       = (const float*)d_in[16];
    const float* kb2       = (const float*)d_in[17];
    const float* vW1       = (const float*)d_in[18];
    const float* vb1       = (const float*)d_in[19];
    const float* vW2       = (const float*)d_in[20];
    const float* vb2       = (const float*)d_in[21];
    const float* gk        = (const float*)d_in[22];
    const float* gv        = (const float*)d_in[23];
    const float* log_temp  = (const float*)d_in[24];

    float* out   = (float*)d_out;
    float* memb  = out;                          // mem, later overwritten by mem_k
    float* outv  = out + (size_t)21760 * 1024;   // mem_v region (hosts query_bf first)

    // ---- workspace layout (floats) ----
    float* w      = (float*)d_ws;
    u16*   kc_bf  = (u16*)w;                     // [0, 5,242,880)
    u16*   vcT_bf = (u16*)(w + 5242880);         // [5,242,880, 10,485,760)
    float* sk     = w + 10485760;                // 327,680
    float* sv     = w + 10813440;                // 327,680
    float* svT    = w + 11141120;                // 327,680
    u16*   sk_bf  = (u16*)(w + 11468800);        // 163,840 f-equiv
    u16*   svT_bf = (u16*)(w + 11632640);        // 163,840 f-equiv
    float* alph   = w + 11796480;                // 21,760
    // 11,818,240..11,859,200 spare (was bias2)
    float* logits = w + 11859200;                // 13,926,400 (ends 25,785,600)
    // tail region (alpha-path statics), after logits:
    float* tail0  = w + 25785600;
    u16*   aW1topT = (u16*)tail0;                // 131,072 u16 = 65,536 f
    u16*   aW1midT = (u16*)(tail0 + 65536);
    u16*   aW1botT = (u16*)(tail0 + 131072);
    float* ceW    = tail0 + 196608;              // 22*128 = 2,816
    float* seW    = tail0 + 199424;              // 10*128 = 1,280
    float* cb     = tail0 + 200704;              // 128
    u16*   h_bf   = (u16*)(tail0 + 200832);      // 21760*128 u16 = 1,392,640 f
    if (ws_size < (size_t)29881600 * 4) return;
    if (out_size < 2 * 21760 * 1024 + 2) return;

    // --- overlays (lifetime-disjoint with their hosts) ---
    u16*   x_bf   = (u16*)logits;                // dead before gemm_logits
    float* bufA   = logits + 5570560;            // catBK  2,621,440
    float* bufB   = bufA + 2621440;              // catBV  2,621,440
    float* catBVT = bufB + 2621440;              // 2,621,440
    u16*   WqT    = (u16*)w;                     // dead before build_kc
    u16*   WkT    = WqT + 1048576;
    u16*   WvT    = WkT + 1048576;
    u16*   kW1T   = (u16*)sv;                    // written after sv consumed
    u16*   vW1T   = kW1T + 65536;                // contiguous with kW1T => [128][1024]
    u16*   kW2T   = vW1T + 65536;
    u16*   vW2T   = kW2T + 65536;
    float* bufAB  = w;                           // [21760][128] head hidden, <= kc region
    u16*   query_bf = (u16*)outv;                // dead before final mem_v gemm

    const dim3 blk256(256);

    // 0. casts / weight transposes (tcast grid = (Cc/32, R/32))
    castbf<<<dim3(2048), blk256, 0, stream>>>(x, x_bf, 21760 * 1024 / 4);
    tcast<<<dim3(32, 32), blk256, 0, stream>>>(Wq, WqT, 1024, 1024);
    tcast<<<dim3(32, 32), blk256, 0, stream>>>(Wk, WkT, 1024, 1024);
    tcast<<<dim3(32, 32), blk256, 0, stream>>>(Wv, WvT, 1024, 1024);
    tcast<<<dim3(4, 32), blk256, 0, stream>>>(aW1,              aW1topT, 1024, 128);
    tcast<<<dim3(4, 32), blk256, 0, stream>>>(aW1 + 1024 * 128, aW1midT, 1024, 128);
    tcast<<<dim3(4, 32), blk256, 0, stream>>>(aW1 + 2048 * 128, aW1botT, 1024, 128);

    // 1. projections (MFMA); query written directly as bf16
    gemm_mfma<0,1><<<dim3(170, 8), blk256, 0, stream>>>(x_bf, WqT, (float*)query_bf, 21760, 1024, 1024, 1024, nullptr, nullptr);
    gemm_mfma<1,0><<<dim3(3, 8),   blk256, 0, stream>>>(sm,   WkT, sk,   320,  1024, 1024, 1024, nullptr, nullptr);
    gemm_mfma<1,0><<<dim3(3, 8),   blk256, 0, stream>>>(sm,   WvT, sv,   320,  1024, 1024, 1024, nullptr, nullptr);
    gemm_mfma<1,0><<<dim3(20, 8),  blk256, 0, stream>>>(cat_B, WkT, bufA, 2560, 1024, 1024, 1024, nullptr, nullptr);
    gemm_mfma<1,0><<<dim3(20, 8),  blk256, 0, stream>>>(cat_B, WvT, bufB, 2560, 1024, 1024, 1024, nullptr, nullptr);

    // 1b. alpha-path statics: ceW = cat_emb @ aW1_mid, seW = scale_emb @ aW1_bot + ab1
    gemm_mfma<1,0><<<dim3(1, 1), blk256, 0, stream>>>(cat_emb,   aW1midT, ceW, 22, 128, 1024, 1024, nullptr, nullptr);
    gemm_mfma<1,0><<<dim3(1, 1), blk256, 0, stream>>>(scale_emb, aW1botT, seW, 10, 128, 1024, 1024, ab1, nullptr);

    // 2. derived key/value layouts
    castbf<<<dim3(320), blk256, 0, stream>>>(sk, sk_bf, 320 * 1024 / 4);
    transpose32<<<dim3(32, 10), blk256, 0, stream>>>(sv, svT, 320, 1024);
    tcast<<<dim3(32, 10), blk256, 0, stream>>>(sv, svT_bf, 320, 1024);
    transpose32<<<dim3(32, 80), blk256, 0, stream>>>(bufB, catBVT, 2560, 1024);
    // small head-weight transposes AFTER sv is consumed (they overlay sv)
    tcast<<<dim3(2, 32), blk256, 0, stream>>>(kW1, kW1T, 1024, 64);
    tcast<<<dim3(2, 32), blk256, 0, stream>>>(vW1, vW1T, 1024, 64);
    tcast<<<dim3(32, 2), blk256, 0, stream>>>(kW2, kW2T, 64, 1024);
    tcast<<<dim3(32, 2), blk256, 0, stream>>>(vW2, vW2T, 64, 1024);
    concat_bias<<<dim3(1), dim3(128), 0, stream>>>(kb1, vb1, cb);

    // 3. per-batch low-rank expanded K (row-major bf16) / V (transposed bf16)
    build_kc<<<dim3(NB, 320), blk256, 0, stream>>>(sk, bufA, cat_A, cat_ids, kc_bf);
    build_vcT<<<dim3(NB, 1024), dim3(320), 0, stream>>>(svT, catBVT, cat_A, cat_ids, vcT_bf);

    // 4. alpha gate (MFMA hidden + tiny reduce)
    gemm_halpha<<<dim3(170), blk256, 0, stream>>>(query_bf, aW1topT, ceW, seW, cat_ids, h_bf);
    alpha_reduce<<<dim3(5440), blk256, 0, stream>>>(h_bf, aW2, ab2, cat_ids, alph);

    // 5. attention as MFMA GEMMs: logits -> masked softmax (P in-place) -> PV
    gemm_logits<<<dim3(6, 5, NB), blk256, 0, stream>>>(query_bf, sk_bf, kc_bf, logits);
    softmax_kernel<<<dim3(170, NB), blk256, 0, stream>>>(logits, alph, log_temp);
    gemm_pv<<<dim3(6, 8, NB), blk256, 0, stream>>>((const u16*)logits, svT_bf, vcT_bf, memb);

    // 6. final low-rank projections: fused stage-1 (N=128), then two stage-2
    gemm_mfma<1,0><<<dim3(170, 1), blk256, 0, stream>>>(memb, kW1T, bufAB, 21760, 128, 1024, 1024, cb, nullptr);
    gemm_mfma<1,0><<<dim3(170, 8), blk256, 0, stream>>>(bufAB,      kW2T, memb, 21760, 1024, 64, 128, kb2, gk);
    gemm_mfma<1,0><<<dim3(170, 8), blk256, 0, stream>>>(bufAB + 64, vW2T, outv, 21760, 1024, 64, 128, vb2, gv);

    tail_zero<<<1, 64, 0, stream>>>(out + (size_t)2 * 21760 * 1024);
}

// Round 3
// 1045.895 us; speedup vs baseline: 2.0581x; 1.0524x over previous
//
#include <hip/hip_runtime.h>
#include <math.h>

// Problem constants
#define NB 32          // batch
#define NC 1024        // channels
#define LTOT 680       // total tokens per batch

typedef unsigned short u16;
typedef __bf16 bf16x8 __attribute__((ext_vector_type(8)));
typedef float floatx4 __attribute__((ext_vector_type(4)));

__device__ __forceinline__ u16 f2bf(float f)
{
    union { float f; unsigned u; } v; v.f = f;
    unsigned u = v.u;
    u += 0x7FFFu + ((u >> 16) & 1u);   // RNE
    return (u16)(u >> 16);
}

__device__ __forceinline__ float bf2f(unsigned u)
{
    union { unsigned u; float f; } v; v.u = u << 16; return v.f;
}

// ---------------------------------------------------------------------------
// Async global->LDS 16B copy. LDS dest is wave-uniform base + lane*16 (HW
// semantics); global src is per-lane. LDS ptr: generic->as3 via low-32 trunc
// (LLVM lowers generic LDS addresses with offset in low 32 bits).
// ---------------------------------------------------------------------------
__device__ __forceinline__ void gload16(const u16* g, u16* l)
{
    typedef __attribute__((address_space(1))) const void gv_t;
    typedef __attribute__((address_space(3))) void lv_t;
    __builtin_amdgcn_global_load_lds(
        (gv_t*)(unsigned long long)(const void*)g,
        (lv_t*)(unsigned int)(unsigned long long)(void*)l,
        16, 0, 0);
}

// Inverse of the frag-order LDS map: slot s -> (row, k-chunk cq).
// Forward: slot = ((row>>4)*2 + (cq>>2))*64 + (cq&3)*16 + (row&15)
__device__ __forceinline__ void slot_decode(int s, int* prow, int* pcq)
{
    *prow = ((s >> 7) << 4) | (s & 15);
    *pcq  = (((s >> 6) & 1) << 2) | ((s >> 4) & 3);
}

// ---------------------------------------------------------------------------
// bf16 MFMA GEMM: C[MxN] = A[MxK] @ B, B given as BT[NxK] bf16 row-major.
// 128x128 tile, BK=64, 256 threads = 4 waves (2x2 wave grid).
// m0 from blockIdx.y, n0 from blockIdx.x (XCD strip mapping for 8-wide grids).
// bf16-A path stages BOTH tiles via global_load_lds with pre-swizzled per-lane
// source addresses (linear LDS dest == frag order); no VALU staging, no LDS
// write conflicts. AFP32=1 keeps the fp32 inline-cast staging for A.
// OUTBF=1: C stored bf16. lda = A row stride. K multiple of 64.
// ---------------------------------------------------------------------------
template<int AFP32, int OUTBF>
__global__ __launch_bounds__(256) void gemm_mfma(
    const void* __restrict__ Av, const u16* __restrict__ BT,
    float* __restrict__ C, int M, int N, int K, int lda,
    const float* __restrict__ bias, const float* __restrict__ scale_logit)
{
    __shared__ __align__(16) u16 As[16 * 64 * 8];   // 16KB
    __shared__ __align__(16) u16 Bs[16 * 64 * 8];   // 16KB

    const int tid  = threadIdx.x;
    const int m0   = blockIdx.y << 7;
    const int n0   = blockIdx.x << 7;
    const int wave = tid >> 6;
    const int lane = tid & 63;
    const int mh   = wave & 1;
    const int nh   = wave >> 1;

    // precompute per-lane staging sources (slot = tid + p*256)
    const u16* aSrc[4];
    const u16* bSrc[4];
#pragma unroll
    for (int p = 0; p < 4; ++p) {
        int s, row, cq;
        s = tid + (p << 8);
        slot_decode(s, &row, &cq);
        if (!AFP32) {
            int gr = m0 + row; if (gr > M - 1) gr = M - 1;
            aSrc[p] = (const u16*)Av + (size_t)gr * lda + (cq << 3);
        }
        int gn = n0 + row; if (gn > N - 1) gn = N - 1;
        bSrc[p] = BT + (size_t)gn * K + (cq << 3);
    }

    floatx4 acc[4][4];
#pragma unroll
    for (int i = 0; i < 4; ++i)
#pragma unroll
        for (int j = 0; j < 4; ++j) acc[i][j] = (floatx4){0.f, 0.f, 0.f, 0.f};

    for (int k0 = 0; k0 < K; k0 += 64) {
        __syncthreads();
        if (AFP32) {
            const float* A = (const float*)Av;
#pragma unroll
            for (int p = 0; p < 8; ++p) {
                int q   = tid + (p << 8);          // 2048 chunks of 4 floats
                int row = q >> 4;
                int fq  = q & 15;
                int gr  = m0 + row; if (gr > M - 1) gr = M - 1;
                const float4 a4 = *(const float4*)(A + (size_t)gr * lda + k0 + (fq << 2));
                int kh = fq >> 3, quad = (fq >> 1) & 3, jh = fq & 1;
                u16* d = &As[((((row >> 4) << 1) | kh) * 64 + (quad << 4) + (row & 15)) * 8 + (jh << 2)];
                d[0] = f2bf(a4.x); d[1] = f2bf(a4.y); d[2] = f2bf(a4.z); d[3] = f2bf(a4.w);
            }
        } else {
#pragma unroll
            for (int p = 0; p < 4; ++p)
                gload16(aSrc[p] + k0, As + ((wave << 6) + (p << 8)) * 8);
        }
#pragma unroll
        for (int p = 0; p < 4; ++p)
            gload16(bSrc[p] + k0, Bs + ((wave << 6) + (p << 8)) * 8);
        __syncthreads();
#pragma unroll
        for (int kh = 0; kh < 2; ++kh) {
            bf16x8 a[4], b[4];
#pragma unroll
            for (int i = 0; i < 4; ++i)
                a[i] = *(const bf16x8*)&As[(((((mh << 2) + i) << 1) | kh) * 64 + lane) * 8];
#pragma unroll
            for (int j = 0; j < 4; ++j)
                b[j] = *(const bf16x8*)&Bs[(((((nh << 2) + j) << 1) | kh) * 64 + lane) * 8];
#pragma unroll
            for (int i = 0; i < 4; ++i)
#pragma unroll
                for (int j = 0; j < 4; ++j)
                    acc[i][j] = __builtin_amdgcn_mfma_f32_16x16x32_bf16(a[i], b[j], acc[i][j], 0, 0, 0);
        }
    }

    float scale = 1.f;
    if (scale_logit) scale = 1.f / (1.f + __expf(-scale_logit[0]));
    const int col = lane & 15, rquad = lane >> 4;
#pragma unroll
    for (int i = 0; i < 4; ++i) {
#pragma unroll
        for (int j = 0; j < 4; ++j) {
#pragma unroll
            for (int r = 0; r < 4; ++r) {
                int gr = m0 + (mh << 6) + (i << 4) + (rquad << 2) + r;
                int gc = n0 + (nh << 6) + (j << 4) + col;
                if (gr < M && gc < N) {
                    float bb = bias ? bias[gc] : 0.f;
                    float val = scale * (acc[i][j][r] + bb);
                    if (OUTBF) ((u16*)C)[(size_t)gr * N + gc] = f2bf(val);
                    else       C[(size_t)gr * N + gc] = val;
                }
            }
        }
    }
}

// ---------------------------------------------------------------------------
// Batched logits GEMM: out[b][680][640] = Q_b[680x1024] @ [sk ; kc_b]^T.
// ---------------------------------------------------------------------------
__global__ __launch_bounds__(256) void gemm_logits(
    const u16* __restrict__ Q, const u16* __restrict__ skb,
    const u16* __restrict__ kcb, float* __restrict__ out)
{
    __shared__ __align__(16) u16 As[16 * 64 * 8];
    __shared__ __align__(16) u16 Bs[16 * 64 * 8];

    const int tid  = threadIdx.x;
    const int m0   = blockIdx.x << 7;
    const int n0   = blockIdx.y << 7;
    const int b    = blockIdx.z;
    const int wave = tid >> 6;
    const int lane = tid & 63;
    const int mh   = wave & 1;
    const int nh   = wave >> 1;

    const u16* Ab = Q   + (size_t)b * 680 * 1024;
    const u16* KC = kcb + (size_t)b * 320 * 1024;

    const u16* aSrc[4];
    const u16* bSrc[4];
#pragma unroll
    for (int p = 0; p < 4; ++p) {
        int s, row, cq;
        s = tid + (p << 8);
        slot_decode(s, &row, &cq);
        int gr = m0 + row; if (gr > 679) gr = 679;
        aSrc[p] = Ab + (size_t)gr * 1024 + (cq << 3);
        int gn = n0 + row;                    // < 640 always
        bSrc[p] = ((gn < 320) ? (skb + (size_t)gn * 1024)
                              : (KC + (size_t)(gn - 320) * 1024)) + (cq << 3);
    }

    floatx4 acc[4][4];
#pragma unroll
    for (int i = 0; i < 4; ++i)
#pragma unroll
        for (int j = 0; j < 4; ++j) acc[i][j] = (floatx4){0.f, 0.f, 0.f, 0.f};

    for (int k0 = 0; k0 < 1024; k0 += 64) {
        __syncthreads();
#pragma unroll
        for (int p = 0; p < 4; ++p)
            gload16(aSrc[p] + k0, As + ((wave << 6) + (p << 8)) * 8);
#pragma unroll
        for (int p = 0; p < 4; ++p)
            gload16(bSrc[p] + k0, Bs + ((wave << 6) + (p << 8)) * 8);
        __syncthreads();
#pragma unroll
        for (int kh = 0; kh < 2; ++kh) {
            bf16x8 a[4], bb[4];
#pragma unroll
            for (int i = 0; i < 4; ++i)
                a[i] = *(const bf16x8*)&As[(((((mh << 2) + i) << 1) | kh) * 64 + lane) * 8];
#pragma unroll
            for (int j = 0; j < 4; ++j)
                bb[j] = *(const bf16x8*)&Bs[(((((nh << 2) + j) << 1) | kh) * 64 + lane) * 8];
#pragma unroll
            for (int i = 0; i < 4; ++i)
#pragma unroll
                for (int j = 0; j < 4; ++j)
                    acc[i][j] = __builtin_amdgcn_mfma_f32_16x16x32_bf16(a[i], bb[j], acc[i][j], 0, 0, 0);
        }
    }

    const int col = lane & 15, rquad = lane >> 4;
#pragma unroll
    for (int i = 0; i < 4; ++i)
#pragma unroll
        for (int j = 0; j < 4; ++j)
#pragma unroll
            for (int r = 0; r < 4; ++r) {
                int gr = m0 + (mh << 6) + (i << 4) + (rquad << 2) + r;
                int gc = n0 + (nh << 6) + (j << 4) + col;
                if (gr < 680)
                    out[((size_t)b * 680 + gr) * 640 + gc] = acc[i][j][r];
            }
}

// ---------------------------------------------------------------------------
// Batched PV GEMM: mem[b][680][1024] bf16 = P_b[680x640] @ [sv ; vc_b].
// A = P bf16, row stride 1280 u16 (in-place over fp32 logits rows).
// ---------------------------------------------------------------------------
__global__ __launch_bounds__(256) void gemm_pv(
    const u16* __restrict__ P, const u16* __restrict__ svT,
    const u16* __restrict__ vcT, u16* __restrict__ out)
{
    __shared__ __align__(16) u16 As[16 * 64 * 8];
    __shared__ __align__(16) u16 Bs[16 * 64 * 8];

    const int tid  = threadIdx.x;
    const int m0   = blockIdx.x << 7;
    const int n0   = blockIdx.y << 7;
    const int b    = blockIdx.z;
    const int wave = tid >> 6;
    const int lane = tid & 63;
    const int mh   = wave & 1;
    const int nh   = wave >> 1;

    const u16* aSrc[4];
    const u16* bSrcS[4];
    const u16* bSrcC[4];
#pragma unroll
    for (int p = 0; p < 4; ++p) {
        int s, row, cq;
        s = tid + (p << 8);
        slot_decode(s, &row, &cq);
        int gr = m0 + row; if (gr > 679) gr = 679;
        aSrc[p] = P + ((size_t)b * 680 + gr) * 1280 + (cq << 3);
        int gn = n0 + row;                    // < 1024 always
        bSrcS[p] = svT + (size_t)gn * 320 + (cq << 3);
        bSrcC[p] = vcT + ((size_t)b * 1024 + gn) * 320 + (cq << 3);
    }

    floatx4 acc[4][4];
#pragma unroll
    for (int i = 0; i < 4; ++i)
#pragma unroll
        for (int j = 0; j < 4; ++j) acc[i][j] = (floatx4){0.f, 0.f, 0.f, 0.f};

    for (int k0 = 0; k0 < 640; k0 += 64) {
        __syncthreads();
#pragma unroll
        for (int p = 0; p < 4; ++p)
            gload16(aSrc[p] + k0, As + ((wave << 6) + (p << 8)) * 8);
#pragma unroll
        for (int p = 0; p < 4; ++p) {
            const u16* bp = (k0 < 320) ? (bSrcS[p] + k0) : (bSrcC[p] + (k0 - 320));
            gload16(bp, Bs + ((wave << 6) + (p << 8)) * 8);
        }
        __syncthreads();
#pragma unroll
        for (int kh = 0; kh < 2; ++kh) {
            bf16x8 a[4], bb[4];
#pragma unroll
            for (int i = 0; i < 4; ++i)
                a[i] = *(const bf16x8*)&As[(((((mh << 2) + i) << 1) | kh) * 64 + lane) * 8];
#pragma unroll
            for (int j = 0; j < 4; ++j)
                bb[j] = *(const bf16x8*)&Bs[(((((nh << 2) + j) << 1) | kh) * 64 + lane) * 8];
#pragma unroll
            for (int i = 0; i < 4; ++i)
#pragma unroll
                for (int j = 0; j < 4; ++j)
                    acc[i][j] = __builtin_amdgcn_mfma_f32_16x16x32_bf16(a[i], bb[j], acc[i][j], 0, 0, 0);
        }
    }

    const int col = lane & 15, rquad = lane >> 4;
#pragma unroll
    for (int i = 0; i < 4; ++i)
#pragma unroll
        for (int j = 0; j < 4; ++j)
#pragma unroll
            for (int r = 0; r < 4; ++r) {
                int gr = m0 + (mh << 6) + (i << 4) + (rquad << 2) + r;
                int gc = n0 + (nh << 6) + (j << 4) + col;
                if (gr < 680)
                    out[((size_t)b * 680 + gr) * 1024 + gc] = f2bf(acc[i][j][r]);
            }
}

// ---------------------------------------------------------------------------
// Alpha hidden GEMM: h[21760][128] bf16 = gelu( Q @ aW1_topT
//                     + ceW[cid[b]] + seW[isc(l)] )   (seW includes ab1)
// M=21760, N=128, K=1024 fixed; grid (170).
// ---------------------------------------------------------------------------
__global__ __launch_bounds__(256) void gemm_halpha(
    const u16* __restrict__ Q, const u16* __restrict__ W,
    const float* __restrict__ ceW, const float* __restrict__ seW,
    const int* __restrict__ cat_ids, u16* __restrict__ h)
{
    __shared__ __align__(16) u16 As[16 * 64 * 8];
    __shared__ __align__(16) u16 Bs[16 * 64 * 8];

    const int tid  = threadIdx.x;
    const int m0   = blockIdx.x << 7;
    const int wave = tid >> 6;
    const int lane = tid & 63;
    const int mh   = wave & 1;
    const int nh   = wave >> 1;

    const u16* aSrc[4];
    const u16* bSrc[4];
#pragma unroll
    for (int p = 0; p < 4; ++p) {
        int s, row, cq;
        s = tid + (p << 8);
        slot_decode(s, &row, &cq);
        aSrc[p] = Q + (size_t)(m0 + row) * 1024 + (cq << 3);   // m0+row < 21760
        bSrc[p] = W + (size_t)row * 1024 + (cq << 3);          // row < 128 = N
    }

    floatx4 acc[4][4];
#pragma unroll
    for (int i = 0; i < 4; ++i)
#pragma unroll
        for (int j = 0; j < 4; ++j) acc[i][j] = (floatx4){0.f, 0.f, 0.f, 0.f};

    for (int k0 = 0; k0 < 1024; k0 += 64) {
        __syncthreads();
#pragma unroll
        for (int p = 0; p < 4; ++p)
            gload16(aSrc[p] + k0, As + ((wave << 6) + (p << 8)) * 8);
#pragma unroll
        for (int p = 0; p < 4; ++p)
            gload16(bSrc[p] + k0, Bs + ((wave << 6) + (p << 8)) * 8);
        __syncthreads();
#pragma unroll
        for (int kh = 0; kh < 2; ++kh) {
            bf16x8 a[4], bb[4];
#pragma unroll
            for (int i = 0; i < 4; ++i)
                a[i] = *(const bf16x8*)&As[(((((mh << 2) + i) << 1) | kh) * 64 + lane) * 8];
#pragma unroll
            for (int j = 0; j < 4; ++j)
                bb[j] = *(const bf16x8*)&Bs[(((((nh << 2) + j) << 1) | kh) * 64 + lane) * 8];
#pragma unroll
            for (int i = 0; i < 4; ++i)
#pragma unroll
                for (int j = 0; j < 4; ++j)
                    acc[i][j] = __builtin_amdgcn_mfma_f32_16x16x32_bf16(a[i], bb[j], acc[i][j], 0, 0, 0);
        }
    }

    const int se_[9] = {1,5,14,30,55,91,155,255,424};
    const int col = lane & 15, rquad = lane >> 4;
#pragma unroll
    for (int i = 0; i < 4; ++i) {
#pragma unroll
        for (int r = 0; r < 4; ++r) {
            int gr = m0 + (mh << 6) + (i << 4) + (rquad << 2) + r;
            int b  = gr / 680;
            int l  = gr - b * 680;
            int isc = 0;
#pragma unroll
            for (int k = 0; k < 9; ++k) if (l >= se_[k]) isc = k + 1;
            int cid = cat_ids[b]; if (cid < 0) cid = 0;
            const float* cw = ceW + cid * 128;
            const float* sw = seW + isc * 128;
#pragma unroll
            for (int j = 0; j < 4; ++j) {
                int gc = (nh << 6) + (j << 4) + col;
                float val = acc[i][j][r] + cw[gc] + sw[gc];
                float g = 0.5f * val * (1.0f + erff(val * 0.70710678118654752f));
                h[(size_t)gr * 128 + gc] = f2bf(g);
            }
        }
    }
}

// ---------------------------------------------------------------------------
// alpha[row] = valid ? sigmoid( dot(h[row], aW2) + ab2 ) : 0.
// ---------------------------------------------------------------------------
__global__ __launch_bounds__(256) void alpha_reduce(
    const u16* __restrict__ h, const float* __restrict__ aW2,
    const float* __restrict__ ab2, const int* __restrict__ cat_ids,
    float* __restrict__ alpha)
{
    const int wave = threadIdx.x >> 6;
    const int lane = threadIdx.x & 63;
    const int row  = (blockIdx.x << 2) + wave;   // < 21760 exact

    const unsigned pk = *(const unsigned*)(h + (size_t)row * 128 + (lane << 1));
    float s = bf2f(pk) * aW2[lane << 1] + bf2f(pk >> 16) * aW2[(lane << 1) + 1];
#pragma unroll
    for (int k = 32; k >= 1; k >>= 1) s += __shfl_xor(s, k);
    if (lane == 0) {
        int b = row / 680;
        float al = 0.f;
        if (cat_ids[b] >= 0) al = 1.f / (1.f + expf(-(s + ab2[0])));
        alpha[row] = al;
    }
}

// ---------------------------------------------------------------------------
// Masked dual softmax, one wave per token row; folds alpha into P.
// Reads logits row [640] fp32, writes P row [640] bf16 IN PLACE.
// ---------------------------------------------------------------------------
__global__ __launch_bounds__(256) void softmax_kernel(
    float* __restrict__ logits, const float* __restrict__ alpha,
    const float* __restrict__ log_temp)
{
    const int tid  = threadIdx.x;
    const int w    = tid >> 6;
    const int lane = tid & 63;
    const int b    = blockIdx.y;
    const int l    = (blockIdx.x << 2) + w;     // 680 = 170*4, exact

    const int se[10] = {1,5,14,30,55,91,155,255,424,680};
    int isc = 0;
#pragma unroll
    for (int k = 0; k < 9; ++k) if (l >= se[k]) isc = k + 1;
    const int NK = (isc + 1) << 5;

    float temp = __expf(log_temp[0]);
    temp = fminf(fmaxf(temp, 0.05f), 1.0f);
    const float Ksc = 0.03125f / temp;

    float* row = logits + ((size_t)b * 680 + l) * 640;

    float ls[5], lc[5];
#pragma unroll
    for (int u = 0; u < 5; ++u) {
        int j = lane + (u << 6);
        bool v = j < NK;
        ls[u] = v ? row[j]       : -1e30f;
        lc[u] = v ? row[320 + j] : -1e30f;
    }
    float mxs = -1e30f, mxc = -1e30f;
#pragma unroll
    for (int u = 0; u < 5; ++u) { mxs = fmaxf(mxs, ls[u]); mxc = fmaxf(mxc, lc[u]); }
#pragma unroll
    for (int k = 32; k >= 1; k >>= 1) {
        mxs = fmaxf(mxs, __shfl_xor(mxs, k));
        mxc = fmaxf(mxc, __shfl_xor(mxc, k));
    }
    float es[5], ec[5], ss = 0.f, sc = 0.f;
#pragma unroll
    for (int u = 0; u < 5; ++u) {
        int j = lane + (u << 6);
        bool v = j < NK;
        es[u] = v ? __expf((ls[u] - mxs) * Ksc) : 0.f;
        ec[u] = v ? __expf((lc[u] - mxc) * Ksc) : 0.f;
        ss += es[u]; sc += ec[u];
    }
#pragma unroll
    for (int k = 32; k >= 1; k >>= 1) {
        ss += __shfl_xor(ss, k);
        sc += __shfl_xor(sc, k);
    }
    const float al = alpha[b * LTOT + l];
    const float wS = (1.f - al) / ss;
    const float wC = al / sc;

    u16* po = (u16*)row;
#pragma unroll
    for (int u = 0; u < 5; ++u) {
        int j = lane + (u << 6);
        po[j]       = f2bf(es[u] * wS);
        po[320 + j] = f2bf(ec[u] * wC);
    }
}

// ---------------------------------------------------------------------------
// fp32 elementwise -> bf16 (n4 = element count / 4)
// ---------------------------------------------------------------------------
__global__ __launch_bounds__(256) void castbf(
    const float* __restrict__ in, u16* __restrict__ out, int n4)
{
    int i = blockIdx.x * 256 + threadIdx.x;
    const int stride = gridDim.x * 256;
    for (; i < n4; i += stride) {
        const float4 v = ((const float4*)in)[i];
        uint2 o;
        o.x = (unsigned)f2bf(v.x) | ((unsigned)f2bf(v.y) << 16);
        o.y = (unsigned)f2bf(v.z) | ((unsigned)f2bf(v.w) << 16);
        ((uint2*)out)[i] = o;
    }
}

// ---------------------------------------------------------------------------
// transpose + cast: out[Cc][R] bf16 = in[R][Cc]^T. grid (ceil(Cc/32), ceil(R/32))
// ---------------------------------------------------------------------------
__global__ __launch_bounds__(256) void tcast(
    const float* __restrict__ in, u16* __restrict__ out, int R, int Cc)
{
    __shared__ float t[32][33];
    const int bx = blockIdx.x * 32;   // Cc
    const int by = blockIdx.y * 32;   // R
    const int x = threadIdx.x & 31;
    const int y0 = threadIdx.x >> 5;
#pragma unroll
    for (int yy = y0; yy < 32; yy += 8)
        t[yy][x] = (by + yy < R && bx + x < Cc)
                 ? in[(size_t)(by + yy) * Cc + bx + x] : 0.f;
    __syncthreads();
#pragma unroll
    for (int yy = y0; yy < 32; yy += 8)
        if (bx + yy < Cc && by + x < R)
            out[(size_t)(bx + yy) * R + by + x] = f2bf(t[x][yy]);
}

// ---------------------------------------------------------------------------
// 32x32 fp32 transpose, same grid convention, guarded.
// ---------------------------------------------------------------------------
__global__ __launch_bounds__(256) void transpose32(
    const float* __restrict__ in, float* __restrict__ out, int R, int Cc)
{
    __shared__ float t[32][33];
    const int bx = blockIdx.x * 32;
    const int by = blockIdx.y * 32;
    const int x = threadIdx.x & 31;
    const int y0 = threadIdx.x >> 5;
#pragma unroll
    for (int yy = y0; yy < 32; yy += 8)
        t[yy][x] = (by + yy < R && bx + x < Cc)
                 ? in[(size_t)(by + yy) * Cc + bx + x] : 0.f;
    __syncthreads();
#pragma unroll
    for (int yy = y0; yy < 32; yy += 8)
        if (bx + yy < Cc && by + x < R)
            out[(size_t)(bx + yy) * R + by + x] = t[x][yy];
}

// ---------------------------------------------------------------------------
// kc[b][j][c] bf16 = sk[j][c] + sum_r a[b,v,r] * catBK[(v*8+r)*32+slot][c]
// ---------------------------------------------------------------------------
__global__ __launch_bounds__(256) void build_kc(
    const float* __restrict__ sk, const float* __restrict__ catBK,
    const float* __restrict__ cat_A, const int* __restrict__ cat_ids,
    u16* __restrict__ kc)
{
    const int b = blockIdx.x;
    const int jrow = blockIdx.y;
    const int v = jrow >> 5, slot = jrow & 31;
    int cid = cat_ids[b]; if (cid < 0) cid = 0;
    float a[8];
#pragma unroll
    for (int r = 0; r < 8; ++r) a[r] = cat_A[(cid * 10 + v) * 8 + r];
    const int c = threadIdx.x << 2;
    float4 acc = *(const float4*)(sk + (size_t)jrow * 1024 + c);
#pragma unroll
    for (int r = 0; r < 8; ++r) {
        const float4 bv = *(const float4*)(catBK + (size_t)((v * 8 + r) * 32 + slot) * 1024 + c);
        acc.x = fmaf(a[r], bv.x, acc.x);
        acc.y = fmaf(a[r], bv.y, acc.y);
        acc.z = fmaf(a[r], bv.z, acc.z);
        acc.w = fmaf(a[r], bv.w, acc.w);
    }
    uint2 pk;
    pk.x = (unsigned)f2bf(acc.x) | ((unsigned)f2bf(acc.y) << 16);
    pk.y = (unsigned)f2bf(acc.z) | ((unsigned)f2bf(acc.w) << 16);
    *(uint2*)(kc + ((size_t)b * 320 + jrow) * 1024 + c) = pk;
}

// ---------------------------------------------------------------------------
// vcT[b][c][j] bf16 = svT[c][j] + sum_r a[b,v,r] * catBVT[c][(v*8+r)*32+slot]
// ---------------------------------------------------------------------------
__global__ __launch_bounds__(320) void build_vcT(
    const float* __restrict__ svT, const float* __restrict__ catBVT,
    const float* __restrict__ cat_A, const int* __restrict__ cat_ids,
    u16* __restrict__ vcT)
{
    __shared__ float aS[80];
    const int b = blockIdx.x;
    const int c = blockIdx.y;
    const int tid = threadIdx.x;
    if (tid < 80) {
        int cid = cat_ids[b]; if (cid < 0) cid = 0;
        aS[tid] = cat_A[cid * 80 + tid];
    }
    __syncthreads();
    const int j = tid;
    const int v = j >> 5, slot = j & 31;
    float acc = svT[(size_t)c * 320 + j];
    const float* row = catBVT + (size_t)c * 2560;
#pragma unroll
    for (int r = 0; r < 8; ++r)
        acc = fmaf(aS[v * 8 + r], row[(v * 8 + r) * 32 + slot], acc);
    vcT[((size_t)b * 1024 + c) * 320 + j] = f2bf(acc);
}

// ---------------------------------------------------------------------------
// cb[0:64] = kb1, cb[64:128] = vb1
// ---------------------------------------------------------------------------
__global__ void concat_bias(const float* __restrict__ a,
                            const float* __restrict__ b, float* __restrict__ o)
{
    int t = threadIdx.x;
    if (t < 64) o[t] = a[t];
    else if (t < 128) o[t] = b[t - 64];
}

__global__ void tail_zero(float* p)
{
    if (threadIdx.x < 2) p[threadIdx.x] = 0.f;
}

// ---------------------------------------------------------------------------
extern "C" void kernel_launch(void* const* d_in, const int* in_sizes, int n_in,
                              void* d_out, int out_size, void* d_ws, size_t ws_size,
                              hipStream_t stream)
{
    (void)in_sizes; (void)n_in;
    const float* x         = (const float*)d_in[0];
    const int*   cat_ids   = (const int*)  d_in[1];
    const float* sm        = (const float*)d_in[2];
    const float* cat_A     = (const float*)d_in[3];
    const float* cat_B     = (const float*)d_in[4];
    const float* cat_emb   = (const float*)d_in[5];
    const float* scale_emb = (const float*)d_in[6];
    const float* Wq        = (const float*)d_in[7];
    const float* Wk        = (const float*)d_in[8];
    const float* Wv        = (const float*)d_in[9];
    const float* aW1       = (const float*)d_in[10];
    const float* ab1       = (const float*)d_in[11];
    const float* aW2       = (const float*)d_in[12];
    const float* ab2       = (const float*)d_in[13];
    const float* kW1       = (const float*)d_in[14];
    const float* kb1       = (const float*)d_in[15];
    const float* kW2       = (const float*)d_in[16];
    const float* kb2       = (const float*)d_in[17];
    const float* vW1       = (const float*)d_in[18];
    const float* vb1       = (const float*)d_in[19];
    const float* vW2       = (const float*)d_in[20];
    const float* vb2       = (const float*)d_in[21];
    const float* gk        = (const float*)d_in[22];
    const float* gv        = (const float*)d_in[23];
    const float* log_temp  = (const float*)d_in[24];

    float* out   = (float*)d_out;
    float* memb  = out;                          // mem_bf16 then fp32 mem_k
    float* outv  = out + (size_t)21760 * 1024;   // mem_v region (hosts query_bf first)

    // ---- workspace layout (floats) ----
    float* w      = (float*)d_ws;
    u16*   kc_bf  = (u16*)w;                     // [0, 5,242,880)
    u16*   vcT_bf = (u16*)(w + 5242880);         // [5,242,880, 10,485,760)
    float* sk     = w + 10485760;                // 327,680
    float* sv     = w + 10813440;                // 327,680
    float* svT    = w + 11141120;                // 327,680
    u16*   sk_bf  = (u16*)(w + 11468800);        // 163,840 f-equiv
    u16*   svT_bf = (u16*)(w + 11632640);        // 163,840 f-equiv
    float* alph   = w + 11796480;                // 21,760
    float* logits = w + 11859200;                // 13,926,400 (ends 25,785,600)
    // tail region (alpha-path statics), after logits:
    float* tail0  = w + 25785600;
    u16*   aW1topT = (u16*)tail0;                // 65,536 f each
    u16*   aW1midT = (u16*)(tail0 + 65536);
    u16*   aW1botT = (u16*)(tail0 + 131072);
    float* ceW    = tail0 + 196608;              // 22*128
    float* seW    = tail0 + 199424;              // 10*128
    float* cb     = tail0 + 200704;              // 128
    u16*   h_bf   = (u16*)(tail0 + 200832);      // 1,392,640 f (ends w+27,379,072)
    u16*   catB_bf = (u16*)(w + 27379072);       // 1,310,720 f (ends 28,689,792)
    u16*   sm_bf  = (u16*)(w + 28689792);        // 163,840 f  (ends 28,853,632)
    if (ws_size < (size_t)29881600 * 4) return;
    if (out_size < 2 * 21760 * 1024 + 2) return;

    // --- overlays (lifetime-disjoint with their hosts) ---
    u16*   x_bf   = (u16*)logits;                // dead before gemm_logits
    float* bufA   = logits + 5570560;            // catBK  2,621,440
    float* bufB   = bufA + 2621440;              // catBV  2,621,440
    float* catBVT = bufB + 2621440;              // 2,621,440
    u16*   WqT    = (u16*)w;                     // dead before build_kc
    u16*   WkT    = WqT + 1048576;
    u16*   WvT    = WkT + 1048576;
    u16*   kW1T   = (u16*)sv;                    // written after sv consumed
    u16*   vW1T   = kW1T + 65536;                // contiguous => [128][1024]
    u16*   kW2T   = vW1T + 65536;
    u16*   vW2T   = kW2T + 65536;
    u16*   bufAB_bf = (u16*)w;                   // [21760][128] bf16, <= kc region
    u16*   mem_bf = (u16*)memb;                  // bf16 mem in d_out first half
    u16*   query_bf = (u16*)outv;                // dead before final mem_v gemm

    const dim3 blk256(256);

    // 0. casts / weight transposes (tcast grid = (Cc/32, R/32))
    castbf<<<dim3(2048), blk256, 0, stream>>>(x, x_bf, 21760 * 1024 / 4);
    castbf<<<dim3(320), blk256, 0, stream>>>(sm, sm_bf, 320 * 1024 / 4);
    castbf<<<dim3(2048), blk256, 0, stream>>>(cat_B, catB_bf, 2560 * 1024 / 4);
    tcast<<<dim3(32, 32), blk256, 0, stream>>>(Wq, WqT, 1024, 1024);
    tcast<<<dim3(32, 32), blk256, 0, stream>>>(Wk, WkT, 1024, 1024);
    tcast<<<dim3(32, 32), blk256, 0, stream>>>(Wv, WvT, 1024, 1024);
    tcast<<<dim3(4, 32), blk256, 0, stream>>>(aW1,              aW1topT, 1024, 128);
    tcast<<<dim3(4, 32), blk256, 0, stream>>>(aW1 + 1024 * 128, aW1midT, 1024, 128);
    tcast<<<dim3(4, 32), blk256, 0, stream>>>(aW1 + 2048 * 128, aW1botT, 1024, 128);

    // 1. projections (MFMA, gload staging); grid = (n_blocks, m_blocks)
    gemm_mfma<0,1><<<dim3(8, 170), blk256, 0, stream>>>(x_bf,    WqT, (float*)query_bf, 21760, 1024, 1024, 1024, nullptr, nullptr);
    gemm_mfma<0,0><<<dim3(8, 3),   blk256, 0, stream>>>(sm_bf,   WkT, sk,   320,  1024, 1024, 1024, nullptr, nullptr);
    gemm_mfma<0,0><<<dim3(8, 3),   blk256, 0, stream>>>(sm_bf,   WvT, sv,   320,  1024, 1024, 1024, nullptr, nullptr);
    gemm_mfma<0,0><<<dim3(8, 20),  blk256, 0, stream>>>(catB_bf, WkT, bufA, 2560, 1024, 1024, 1024, nullptr, nullptr);
    gemm_mfma<0,0><<<dim3(8, 20),  blk256, 0, stream>>>(catB_bf, WvT, bufB, 2560, 1024, 1024, 1024, nullptr, nullptr);

    // 1b. alpha-path statics (tiny, fp32-A path)
    gemm_mfma<1,0><<<dim3(1, 1), blk256, 0, stream>>>(cat_emb,   aW1midT, ceW, 22, 128, 1024, 1024, nullptr, nullptr);
    gemm_mfma<1,0><<<dim3(1, 1), blk256, 0, stream>>>(scale_emb, aW1botT, seW, 10, 128, 1024, 1024, ab1, nullptr);

    // 2. derived key/value layouts
    castbf<<<dim3(320), blk256, 0, stream>>>(sk, sk_bf, 320 * 1024 / 4);
    transpose32<<<dim3(32, 10), blk256, 0, stream>>>(sv, svT, 320, 1024);
    tcast<<<dim3(32, 10), blk256, 0, stream>>>(sv, svT_bf, 320, 1024);
    transpose32<<<dim3(32, 80), blk256, 0, stream>>>(bufB, catBVT, 2560, 1024);
    // small head-weight transposes AFTER sv is consumed (they overlay sv)
    tcast<<<dim3(2, 32), blk256, 0, stream>>>(kW1, kW1T, 1024, 64);
    tcast<<<dim3(2, 32), blk256, 0, stream>>>(vW1, vW1T, 1024, 64);
    tcast<<<dim3(32, 2), blk256, 0, stream>>>(kW2, kW2T, 64, 1024);
    tcast<<<dim3(32, 2), blk256, 0, stream>>>(vW2, vW2T, 64, 1024);
    concat_bias<<<dim3(1), dim3(128), 0, stream>>>(kb1, vb1, cb);

    // 3. per-batch low-rank expanded K (row-major bf16) / V (transposed bf16)
    build_kc<<<dim3(NB, 320), blk256, 0, stream>>>(sk, bufA, cat_A, cat_ids, kc_bf);
    build_vcT<<<dim3(NB, 1024), dim3(320), 0, stream>>>(svT, catBVT, cat_A, cat_ids, vcT_bf);

    // 4. alpha gate (MFMA hidden + tiny reduce)
    gemm_halpha<<<dim3(170), blk256, 0, stream>>>(query_bf, aW1topT, ceW, seW, cat_ids, h_bf);
    alpha_reduce<<<dim3(5440), blk256, 0, stream>>>(h_bf, aW2, ab2, cat_ids, alph);

    // 5. attention as MFMA GEMMs: logits -> masked softmax (P in-place) -> PV
    gemm_logits<<<dim3(6, 5, NB), blk256, 0, stream>>>(query_bf, sk_bf, kc_bf, logits);
    softmax_kernel<<<dim3(170, NB), blk256, 0, stream>>>(logits, alph, log_temp);
    gemm_pv<<<dim3(6, 8, NB), blk256, 0, stream>>>((const u16*)logits, svT_bf, vcT_bf, mem_bf);

    // 6. final low-rank projections: fused bf16 stage-1 (N=128), two stage-2
    gemm_mfma<0,1><<<dim3(1, 170), blk256, 0, stream>>>(mem_bf, kW1T, (float*)bufAB_bf, 21760, 128, 1024, 1024, cb, nullptr);
    gemm_mfma<0,0><<<dim3(8, 170), blk256, 0, stream>>>(bufAB_bf,      kW2T, memb, 21760, 1024, 64, 128, kb2, gk);
    gemm_mfma<0,0><<<dim3(8, 170), blk256, 0, stream>>>(bufAB_bf + 64, vW2T, outv, 21760, 1024, 64, 128, vb2, gv);

    tail_zero<<<1, 64, 0, stream>>>(out + (size_t)2 * 21760 * 1024);
}

// Round 4
// 922.234 us; speedup vs baseline: 2.3341x; 1.1341x over previous
//
#include <hip/hip_runtime.h>
#include <math.h>

// Problem constants
#define NB 32          // batch
#define NC 1024        // channels
#define LTOT 680       // total tokens per batch

typedef unsigned short u16;
typedef __bf16 bf16x8 __attribute__((ext_vector_type(8)));
typedef float floatx4 __attribute__((ext_vector_type(4)));

__device__ __forceinline__ u16 f2bf(float f)
{
    union { float f; unsigned u; } v; v.f = f;
    unsigned u = v.u;
    u += 0x7FFFu + ((u >> 16) & 1u);   // RNE
    return (u16)(u >> 16);
}

__device__ __forceinline__ float bf2f(unsigned u)
{
    union { unsigned u; float f; } v; v.u = u << 16; return v.f;
}

// ---------------------------------------------------------------------------
// Async global->LDS 16B copy. LDS dest is wave-uniform base + lane*16 (HW
// semantics); global src is per-lane.
// ---------------------------------------------------------------------------
__device__ __forceinline__ void gload16(const u16* g, u16* l)
{
    typedef __attribute__((address_space(1))) const void gv_t;
    typedef __attribute__((address_space(3))) void lv_t;
    __builtin_amdgcn_global_load_lds(
        (gv_t*)(unsigned long long)(const void*)g,
        (lv_t*)(unsigned int)(unsigned long long)(void*)l,
        16, 0, 0);
}

// Inverse of the frag-order LDS map: slot s -> (row, k-chunk cq).
// Forward: slot = ((row>>4)*2 + (cq>>2))*64 + (cq&3)*16 + (row&15)
__device__ __forceinline__ void slot_decode(int s, int* prow, int* pcq)
{
    *prow = ((s >> 7) << 4) | (s & 15);
    *pcq  = (((s >> 6) & 1) << 2) | ((s >> 4) & 3);
}

// Pipeline fences: counted wait keeps next-tile loads in flight across the
// barrier (T4); raw s_barrier avoids __syncthreads' vmcnt(0) drain.
#define WAIT_VM8()  asm volatile("s_waitcnt vmcnt(8)" ::: "memory")
#define WAIT_VM0()  asm volatile("s_waitcnt vmcnt(0)" ::: "memory")
#define BAR()       __builtin_amdgcn_s_barrier()
#define SCHEDB()    __builtin_amdgcn_sched_barrier(0)

// ---------------------------------------------------------------------------
// bf16 MFMA GEMM: C[MxN] = A[MxK] @ B, B given as BT[NxK] bf16 row-major.
// 128x128 tile, BK=64, 256 threads = 4 waves (2x2 wave grid).
// Double-buffered LDS, global_load_lds staging with pre-swizzled sources,
// counted-vmcnt 2-phase pipeline.
// OUTBF=1: C stored bf16. lda = A row stride. K multiple of 64.
// ---------------------------------------------------------------------------
template<int OUTBF>
__global__ __launch_bounds__(256) void gemm_mfma(
    const u16* __restrict__ A, const u16* __restrict__ BT,
    float* __restrict__ C, int M, int N, int K, int lda,
    const float* __restrict__ bias, const float* __restrict__ scale_logit)
{
    __shared__ __align__(16) u16 As[2][8192];   // 2 x 16KB
    __shared__ __align__(16) u16 Bs[2][8192];   // 2 x 16KB

    const int tid  = threadIdx.x;
    const int m0   = blockIdx.y << 7;
    const int n0   = blockIdx.x << 7;
    const int wave = tid >> 6;
    const int lane = tid & 63;
    const int mh   = wave & 1;
    const int nh   = wave >> 1;
    const int lbase = (wave << 6) * 8;          // per-wave LDS u16 base

    const u16* aSrc[4];
    const u16* bSrc[4];
#pragma unroll
    for (int p = 0; p < 4; ++p) {
        int s = tid + (p << 8), row, cq;
        slot_decode(s, &row, &cq);
        int gr = m0 + row; if (gr > M - 1) gr = M - 1;
        aSrc[p] = A + (size_t)gr * lda + (cq << 3);
        int gn = n0 + row; if (gn > N - 1) gn = N - 1;
        bSrc[p] = BT + (size_t)gn * K + (cq << 3);
    }

    floatx4 acc[4][4];
#pragma unroll
    for (int i = 0; i < 4; ++i)
#pragma unroll
        for (int j = 0; j < 4; ++j) acc[i][j] = (floatx4){0.f, 0.f, 0.f, 0.f};

    // prologue: stage tile 0 into buf 0
#pragma unroll
    for (int p = 0; p < 4; ++p) gload16(aSrc[p], &As[0][lbase + (p << 11)]);
#pragma unroll
    for (int p = 0; p < 4; ++p) gload16(bSrc[p], &Bs[0][lbase + (p << 11)]);

    const int nt = K >> 6;
    for (int t = 0; t < nt; ++t) {
        const int cur = t & 1;
        if (t + 1 < nt) {
            const int kk = (t + 1) << 6;
#pragma unroll
            for (int p = 0; p < 4; ++p) gload16(aSrc[p] + kk, &As[cur ^ 1][lbase + (p << 11)]);
#pragma unroll
            for (int p = 0; p < 4; ++p) gload16(bSrc[p] + kk, &Bs[cur ^ 1][lbase + (p << 11)]);
            WAIT_VM8();
        } else {
            WAIT_VM0();
        }
        BAR(); SCHEDB();
#pragma unroll
        for (int kh = 0; kh < 2; ++kh) {
            bf16x8 a[4], b[4];
#pragma unroll
            for (int i = 0; i < 4; ++i)
                a[i] = *(const bf16x8*)&As[cur][(((((mh << 2) + i) << 1) | kh) * 64 + lane) * 8];
#pragma unroll
            for (int j = 0; j < 4; ++j)
                b[j] = *(const bf16x8*)&Bs[cur][(((((nh << 2) + j) << 1) | kh) * 64 + lane) * 8];
#pragma unroll
            for (int i = 0; i < 4; ++i)
#pragma unroll
                for (int j = 0; j < 4; ++j)
                    acc[i][j] = __builtin_amdgcn_mfma_f32_16x16x32_bf16(a[i], b[j], acc[i][j], 0, 0, 0);
        }
        SCHEDB(); BAR();
    }

    float scale = 1.f;
    if (scale_logit) scale = 1.f / (1.f + __expf(-scale_logit[0]));
    const int col = lane & 15, rquad = lane >> 4;
#pragma unroll
    for (int i = 0; i < 4; ++i) {
#pragma unroll
        for (int j = 0; j < 4; ++j) {
#pragma unroll
            for (int r = 0; r < 4; ++r) {
                int gr = m0 + (mh << 6) + (i << 4) + (rquad << 2) + r;
                int gc = n0 + (nh << 6) + (j << 4) + col;
                if (gr < M && gc < N) {
                    float bb = bias ? bias[gc] : 0.f;
                    float val = scale * (acc[i][j][r] + bb);
                    if (OUTBF) ((u16*)C)[(size_t)gr * N + gc] = f2bf(val);
                    else       C[(size_t)gr * N + gc] = val;
                }
            }
        }
    }
}

// ---------------------------------------------------------------------------
// Batched logits GEMM: out[b][680][640] = Q_b[680x1024] @ [sk ; kc_b]^T.
// ---------------------------------------------------------------------------
__global__ __launch_bounds__(256) void gemm_logits(
    const u16* __restrict__ Q, const u16* __restrict__ skb,
    const u16* __restrict__ kcb, float* __restrict__ out)
{
    __shared__ __align__(16) u16 As[2][8192];
    __shared__ __align__(16) u16 Bs[2][8192];

    const int tid  = threadIdx.x;
    const int m0   = blockIdx.x << 7;
    const int n0   = blockIdx.y << 7;
    const int b    = blockIdx.z;
    const int wave = tid >> 6;
    const int lane = tid & 63;
    const int mh   = wave & 1;
    const int nh   = wave >> 1;
    const int lbase = (wave << 6) * 8;

    const u16* Ab = Q   + (size_t)b * 680 * 1024;
    const u16* KC = kcb + (size_t)b * 320 * 1024;

    const u16* aSrc[4];
    const u16* bSrc[4];
#pragma unroll
    for (int p = 0; p < 4; ++p) {
        int s = tid + (p << 8), row, cq;
        slot_decode(s, &row, &cq);
        int gr = m0 + row; if (gr > 679) gr = 679;
        aSrc[p] = Ab + (size_t)gr * 1024 + (cq << 3);
        int gn = n0 + row;                    // < 640 always
        bSrc[p] = ((gn < 320) ? (skb + (size_t)gn * 1024)
                              : (KC + (size_t)(gn - 320) * 1024)) + (cq << 3);
    }

    floatx4 acc[4][4];
#pragma unroll
    for (int i = 0; i < 4; ++i)
#pragma unroll
        for (int j = 0; j < 4; ++j) acc[i][j] = (floatx4){0.f, 0.f, 0.f, 0.f};

#pragma unroll
    for (int p = 0; p < 4; ++p) gload16(aSrc[p], &As[0][lbase + (p << 11)]);
#pragma unroll
    for (int p = 0; p < 4; ++p) gload16(bSrc[p], &Bs[0][lbase + (p << 11)]);

    for (int t = 0; t < 16; ++t) {
        const int cur = t & 1;
        if (t < 15) {
            const int kk = (t + 1) << 6;
#pragma unroll
            for (int p = 0; p < 4; ++p) gload16(aSrc[p] + kk, &As[cur ^ 1][lbase + (p << 11)]);
#pragma unroll
            for (int p = 0; p < 4; ++p) gload16(bSrc[p] + kk, &Bs[cur ^ 1][lbase + (p << 11)]);
            WAIT_VM8();
        } else {
            WAIT_VM0();
        }
        BAR(); SCHEDB();
#pragma unroll
        for (int kh = 0; kh < 2; ++kh) {
            bf16x8 a[4], bb[4];
#pragma unroll
            for (int i = 0; i < 4; ++i)
                a[i] = *(const bf16x8*)&As[cur][(((((mh << 2) + i) << 1) | kh) * 64 + lane) * 8];
#pragma unroll
            for (int j = 0; j < 4; ++j)
                bb[j] = *(const bf16x8*)&Bs[cur][(((((nh << 2) + j) << 1) | kh) * 64 + lane) * 8];
#pragma unroll
            for (int i = 0; i < 4; ++i)
#pragma unroll
                for (int j = 0; j < 4; ++j)
                    acc[i][j] = __builtin_amdgcn_mfma_f32_16x16x32_bf16(a[i], bb[j], acc[i][j], 0, 0, 0);
        }
        SCHEDB(); BAR();
    }

    const int col = lane & 15, rquad = lane >> 4;
#pragma unroll
    for (int i = 0; i < 4; ++i)
#pragma unroll
        for (int j = 0; j < 4; ++j)
#pragma unroll
            for (int r = 0; r < 4; ++r) {
                int gr = m0 + (mh << 6) + (i << 4) + (rquad << 2) + r;
                int gc = n0 + (nh << 6) + (j << 4) + col;
                if (gr < 680)
                    out[((size_t)b * 680 + gr) * 640 + gc] = acc[i][j][r];
            }
}

// ---------------------------------------------------------------------------
// Batched PV GEMM: mem[b][680][1024] bf16 = P_b[680x640] @ [sv ; vc_b].
// A = P bf16, row stride 1280 u16 (in-place over fp32 logits rows).
// ---------------------------------------------------------------------------
__global__ __launch_bounds__(256) void gemm_pv(
    const u16* __restrict__ P, const u16* __restrict__ svT,
    const u16* __restrict__ vcT, u16* __restrict__ out)
{
    __shared__ __align__(16) u16 As[2][8192];
    __shared__ __align__(16) u16 Bs[2][8192];

    const int tid  = threadIdx.x;
    const int m0   = blockIdx.x << 7;
    const int n0   = blockIdx.y << 7;
    const int b    = blockIdx.z;
    const int wave = tid >> 6;
    const int lane = tid & 63;
    const int mh   = wave & 1;
    const int nh   = wave >> 1;
    const int lbase = (wave << 6) * 8;

    const u16* aSrc[4];
    const u16* bSrcS[4];
    const u16* bSrcC[4];
#pragma unroll
    for (int p = 0; p < 4; ++p) {
        int s = tid + (p << 8), row, cq;
        slot_decode(s, &row, &cq);
        int gr = m0 + row; if (gr > 679) gr = 679;
        aSrc[p] = P + ((size_t)b * 680 + gr) * 1280 + (cq << 3);
        int gn = n0 + row;                    // < 1024 always
        bSrcS[p] = svT + (size_t)gn * 320 + (cq << 3);
        bSrcC[p] = vcT + ((size_t)b * 1024 + gn) * 320 + (cq << 3);
    }

    floatx4 acc[4][4];
#pragma unroll
    for (int i = 0; i < 4; ++i)
#pragma unroll
        for (int j = 0; j < 4; ++j) acc[i][j] = (floatx4){0.f, 0.f, 0.f, 0.f};

#pragma unroll
    for (int p = 0; p < 4; ++p) gload16(aSrc[p], &As[0][lbase + (p << 11)]);
#pragma unroll
    for (int p = 0; p < 4; ++p) gload16(bSrcS[p], &Bs[0][lbase + (p << 11)]);

    for (int t = 0; t < 10; ++t) {
        const int cur = t & 1;
        if (t < 9) {
            const int tn = t + 1;
            const int kk = tn << 6;
#pragma unroll
            for (int p = 0; p < 4; ++p) gload16(aSrc[p] + kk, &As[cur ^ 1][lbase + (p << 11)]);
#pragma unroll
            for (int p = 0; p < 4; ++p) {
                const u16* bp = (tn < 5) ? (bSrcS[p] + kk) : (bSrcC[p] + ((tn - 5) << 6));
                gload16(bp, &Bs[cur ^ 1][lbase + (p << 11)]);
            }
            WAIT_VM8();
        } else {
            WAIT_VM0();
        }
        BAR(); SCHEDB();
#pragma unroll
        for (int kh = 0; kh < 2; ++kh) {
            bf16x8 a[4], bb[4];
#pragma unroll
            for (int i = 0; i < 4; ++i)
                a[i] = *(const bf16x8*)&As[cur][(((((mh << 2) + i) << 1) | kh) * 64 + lane) * 8];
#pragma unroll
            for (int j = 0; j < 4; ++j)
                bb[j] = *(const bf16x8*)&Bs[cur][(((((nh << 2) + j) << 1) | kh) * 64 + lane) * 8];
#pragma unroll
            for (int i = 0; i < 4; ++i)
#pragma unroll
                for (int j = 0; j < 4; ++j)
                    acc[i][j] = __builtin_amdgcn_mfma_f32_16x16x32_bf16(a[i], bb[j], acc[i][j], 0, 0, 0);
        }
        SCHEDB(); BAR();
    }

    const int col = lane & 15, rquad = lane >> 4;
#pragma unroll
    for (int i = 0; i < 4; ++i)
#pragma unroll
        for (int j = 0; j < 4; ++j)
#pragma unroll
            for (int r = 0; r < 4; ++r) {
                int gr = m0 + (mh << 6) + (i << 4) + (rquad << 2) + r;
                int gc = n0 + (nh << 6) + (j << 4) + col;
                if (gr < 680)
                    out[((size_t)b * 680 + gr) * 1024 + gc] = f2bf(acc[i][j][r]);
            }
}

// ---------------------------------------------------------------------------
// Alpha hidden GEMM: h[21760][128] bf16 = gelu( Q @ aW1_topT
//                     + ceW[cid[b]] + seW[isc(l)] )   (seW includes ab1)
// ---------------------------------------------------------------------------
__global__ __launch_bounds__(256) void gemm_halpha(
    const u16* __restrict__ Q, const u16* __restrict__ W,
    const float* __restrict__ ceW, const float* __restrict__ seW,
    const int* __restrict__ cat_ids, u16* __restrict__ h)
{
    __shared__ __align__(16) u16 As[2][8192];
    __shared__ __align__(16) u16 Bs[2][8192];

    const int tid  = threadIdx.x;
    const int m0   = blockIdx.x << 7;
    const int wave = tid >> 6;
    const int lane = tid & 63;
    const int mh   = wave & 1;
    const int nh   = wave >> 1;
    const int lbase = (wave << 6) * 8;

    const u16* aSrc[4];
    const u16* bSrc[4];
#pragma unroll
    for (int p = 0; p < 4; ++p) {
        int s = tid + (p << 8), row, cq;
        slot_decode(s, &row, &cq);
        aSrc[p] = Q + (size_t)(m0 + row) * 1024 + (cq << 3);   // m0+row < 21760
        bSrc[p] = W + (size_t)row * 1024 + (cq << 3);          // row < 128 = N
    }

    floatx4 acc[4][4];
#pragma unroll
    for (int i = 0; i < 4; ++i)
#pragma unroll
        for (int j = 0; j < 4; ++j) acc[i][j] = (floatx4){0.f, 0.f, 0.f, 0.f};

#pragma unroll
    for (int p = 0; p < 4; ++p) gload16(aSrc[p], &As[0][lbase + (p << 11)]);
#pragma unroll
    for (int p = 0; p < 4; ++p) gload16(bSrc[p], &Bs[0][lbase + (p << 11)]);

    for (int t = 0; t < 16; ++t) {
        const int cur = t & 1;
        if (t < 15) {
            const int kk = (t + 1) << 6;
#pragma unroll
            for (int p = 0; p < 4; ++p) gload16(aSrc[p] + kk, &As[cur ^ 1][lbase + (p << 11)]);
#pragma unroll
            for (int p = 0; p < 4; ++p) gload16(bSrc[p] + kk, &Bs[cur ^ 1][lbase + (p << 11)]);
            WAIT_VM8();
        } else {
            WAIT_VM0();
        }
        BAR(); SCHEDB();
#pragma unroll
        for (int kh = 0; kh < 2; ++kh) {
            bf16x8 a[4], bb[4];
#pragma unroll
            for (int i = 0; i < 4; ++i)
                a[i] = *(const bf16x8*)&As[cur][(((((mh << 2) + i) << 1) | kh) * 64 + lane) * 8];
#pragma unroll
            for (int j = 0; j < 4; ++j)
                bb[j] = *(const bf16x8*)&Bs[cur][(((((nh << 2) + j) << 1) | kh) * 64 + lane) * 8];
#pragma unroll
            for (int i = 0; i < 4; ++i)
#pragma unroll
                for (int j = 0; j < 4; ++j)
                    acc[i][j] = __builtin_amdgcn_mfma_f32_16x16x32_bf16(a[i], bb[j], acc[i][j], 0, 0, 0);
        }
        SCHEDB(); BAR();
    }

    const int se_[9] = {1,5,14,30,55,91,155,255,424};
    const int col = lane & 15, rquad = lane >> 4;
#pragma unroll
    for (int i = 0; i < 4; ++i) {
#pragma unroll
        for (int r = 0; r < 4; ++r) {
            int gr = m0 + (mh << 6) + (i << 4) + (rquad << 2) + r;
            int b  = gr / 680;
            int l  = gr - b * 680;
            int isc = 0;
#pragma unroll
            for (int k = 0; k < 9; ++k) if (l >= se_[k]) isc = k + 1;
            int cid = cat_ids[b]; if (cid < 0) cid = 0;
            const float* cw = ceW + cid * 128;
            const float* sw = seW + isc * 128;
#pragma unroll
            for (int j = 0; j < 4; ++j) {
                int gc = (nh << 6) + (j << 4) + col;
                float val = acc[i][j][r] + cw[gc] + sw[gc];
                float g = 0.5f * val * (1.0f + erff(val * 0.70710678118654752f));
                h[(size_t)gr * 128 + gc] = f2bf(g);
            }
        }
    }
}

// ---------------------------------------------------------------------------
// alpha[row] = valid ? sigmoid( dot(h[row], aW2) + ab2 ) : 0.
// ---------------------------------------------------------------------------
__global__ __launch_bounds__(256) void alpha_reduce(
    const u16* __restrict__ h, const float* __restrict__ aW2,
    const float* __restrict__ ab2, const int* __restrict__ cat_ids,
    float* __restrict__ alpha)
{
    const int wave = threadIdx.x >> 6;
    const int lane = threadIdx.x & 63;
    const int row  = (blockIdx.x << 2) + wave;   // < 21760 exact

    const unsigned pk = *(const unsigned*)(h + (size_t)row * 128 + (lane << 1));
    float s = bf2f(pk) * aW2[lane << 1] + bf2f(pk >> 16) * aW2[(lane << 1) + 1];
#pragma unroll
    for (int k = 32; k >= 1; k >>= 1) s += __shfl_xor(s, k);
    if (lane == 0) {
        int b = row / 680;
        float al = 0.f;
        if (cat_ids[b] >= 0) al = 1.f / (1.f + expf(-(s + ab2[0])));
        alpha[row] = al;
    }
}

// ---------------------------------------------------------------------------
// Masked dual softmax, one wave per token row; folds alpha into P.
// Reads logits row [640] fp32, writes P row [640] bf16 IN PLACE.
// ---------------------------------------------------------------------------
__global__ __launch_bounds__(256) void softmax_kernel(
    float* __restrict__ logits, const float* __restrict__ alpha,
    const float* __restrict__ log_temp)
{
    const int tid  = threadIdx.x;
    const int w    = tid >> 6;
    const int lane = tid & 63;
    const int b    = blockIdx.y;
    const int l    = (blockIdx.x << 2) + w;     // 680 = 170*4, exact

    const int se[10] = {1,5,14,30,55,91,155,255,424,680};
    int isc = 0;
#pragma unroll
    for (int k = 0; k < 9; ++k) if (l >= se[k]) isc = k + 1;
    const int NK = (isc + 1) << 5;

    float temp = __expf(log_temp[0]);
    temp = fminf(fmaxf(temp, 0.05f), 1.0f);
    const float Ksc = 0.03125f / temp;

    float* row = logits + ((size_t)b * 680 + l) * 640;

    float ls[5], lc[5];
#pragma unroll
    for (int u = 0; u < 5; ++u) {
        int j = lane + (u << 6);
        bool v = j < NK;
        ls[u] = v ? row[j]       : -1e30f;
        lc[u] = v ? row[320 + j] : -1e30f;
    }
    float mxs = -1e30f, mxc = -1e30f;
#pragma unroll
    for (int u = 0; u < 5; ++u) { mxs = fmaxf(mxs, ls[u]); mxc = fmaxf(mxc, lc[u]); }
#pragma unroll
    for (int k = 32; k >= 1; k >>= 1) {
        mxs = fmaxf(mxs, __shfl_xor(mxs, k));
        mxc = fmaxf(mxc, __shfl_xor(mxc, k));
    }
    float es[5], ec[5], ss = 0.f, sc = 0.f;
#pragma unroll
    for (int u = 0; u < 5; ++u) {
        int j = lane + (u << 6);
        bool v = j < NK;
        es[u] = v ? __expf((ls[u] - mxs) * Ksc) : 0.f;
        ec[u] = v ? __expf((lc[u] - mxc) * Ksc) : 0.f;
        ss += es[u]; sc += ec[u];
    }
#pragma unroll
    for (int k = 32; k >= 1; k >>= 1) {
        ss += __shfl_xor(ss, k);
        sc += __shfl_xor(sc, k);
    }
    const float al = alpha[b * LTOT + l];
    const float wS = (1.f - al) / ss;
    const float wC = al / sc;

    u16* po = (u16*)row;
#pragma unroll
    for (int u = 0; u < 5; ++u) {
        int j = lane + (u << 6);
        po[j]       = f2bf(es[u] * wS);
        po[320 + j] = f2bf(ec[u] * wC);
    }
}

// ---------------------------------------------------------------------------
// fp32 elementwise -> bf16 (n4 = element count / 4)
// ---------------------------------------------------------------------------
__global__ __launch_bounds__(256) void castbf(
    const float* __restrict__ in, u16* __restrict__ out, int n4)
{
    int i = blockIdx.x * 256 + threadIdx.x;
    const int stride = gridDim.x * 256;
    for (; i < n4; i += stride) {
        const float4 v = ((const float4*)in)[i];
        uint2 o;
        o.x = (unsigned)f2bf(v.x) | ((unsigned)f2bf(v.y) << 16);
        o.y = (unsigned)f2bf(v.z) | ((unsigned)f2bf(v.w) << 16);
        ((uint2*)out)[i] = o;
    }
}

// ---------------------------------------------------------------------------
// transpose + cast: out[Cc][R] bf16 = in[R][Cc]^T. grid (ceil(Cc/32), ceil(R/32))
// ---------------------------------------------------------------------------
__global__ __launch_bounds__(256) void tcast(
    const float* __restrict__ in, u16* __restrict__ out, int R, int Cc)
{
    __shared__ float t[32][33];
    const int bx = blockIdx.x * 32;   // Cc
    const int by = blockIdx.y * 32;   // R
    const int x = threadIdx.x & 31;
    const int y0 = threadIdx.x >> 5;
#pragma unroll
    for (int yy = y0; yy < 32; yy += 8)
        t[yy][x] = (by + yy < R && bx + x < Cc)
                 ? in[(size_t)(by + yy) * Cc + bx + x] : 0.f;
    __syncthreads();
#pragma unroll
    for (int yy = y0; yy < 32; yy += 8)
        if (bx + yy < Cc && by + x < R)
            out[(size_t)(bx + yy) * R + by + x] = f2bf(t[x][yy]);
}

// ---------------------------------------------------------------------------
// 32x32 fp32 transpose, same grid convention, guarded.
// ---------------------------------------------------------------------------
__global__ __launch_bounds__(256) void transpose32(
    const float* __restrict__ in, float* __restrict__ out, int R, int Cc)
{
    __shared__ float t[32][33];
    const int bx = blockIdx.x * 32;
    const int by = blockIdx.y * 32;
    const int x = threadIdx.x & 31;
    const int y0 = threadIdx.x >> 5;
#pragma unroll
    for (int yy = y0; yy < 32; yy += 8)
        t[yy][x] = (by + yy < R && bx + x < Cc)
                 ? in[(size_t)(by + yy) * Cc + bx + x] : 0.f;
    __syncthreads();
#pragma unroll
    for (int yy = y0; yy < 32; yy += 8)
        if (bx + yy < Cc && by + x < R)
            out[(size_t)(bx + yy) * R + by + x] = t[x][yy];
}

// ---------------------------------------------------------------------------
// kc[b][j][c] bf16 = sk[j][c] + sum_r a[b,v,r] * catBK[(v*8+r)*32+slot][c]
// ---------------------------------------------------------------------------
__global__ __launch_bounds__(256) void build_kc(
    const float* __restrict__ sk, const float* __restrict__ catBK,
    const float* __restrict__ cat_A, const int* __restrict__ cat_ids,
    u16* __restrict__ kc)
{
    const int b = blockIdx.x;
    const int jrow = blockIdx.y;
    const int v = jrow >> 5, slot = jrow & 31;
    int cid = cat_ids[b]; if (cid < 0) cid = 0;
    float a[8];
#pragma unroll
    for (int r = 0; r < 8; ++r) a[r] = cat_A[(cid * 10 + v) * 8 + r];
    const int c = threadIdx.x << 2;
    float4 acc = *(const float4*)(sk + (size_t)jrow * 1024 + c);
#pragma unroll
    for (int r = 0; r < 8; ++r) {
        const float4 bv = *(const float4*)(catBK + (size_t)((v * 8 + r) * 32 + slot) * 1024 + c);
        acc.x = fmaf(a[r], bv.x, acc.x);
        acc.y = fmaf(a[r], bv.y, acc.y);
        acc.z = fmaf(a[r], bv.z, acc.z);
        acc.w = fmaf(a[r], bv.w, acc.w);
    }
    uint2 pk;
    pk.x = (unsigned)f2bf(acc.x) | ((unsigned)f2bf(acc.y) << 16);
    pk.y = (unsigned)f2bf(acc.z) | ((unsigned)f2bf(acc.w) << 16);
    *(uint2*)(kc + ((size_t)b * 320 + jrow) * 1024 + c) = pk;
}

// ---------------------------------------------------------------------------
// vcT[b][c][j] bf16 = svT[c][j] + sum_r a[b,v,r] * catBVT[c][(v*8+r)*32+slot]
// ---------------------------------------------------------------------------
__global__ __launch_bounds__(320) void build_vcT(
    const float* __restrict__ svT, const float* __restrict__ catBVT,
    const float* __restrict__ cat_A, const int* __restrict__ cat_ids,
    u16* __restrict__ vcT)
{
    __shared__ float aS[80];
    const int b = blockIdx.x;
    const int c = blockIdx.y;
    const int tid = threadIdx.x;
    if (tid < 80) {
        int cid = cat_ids[b]; if (cid < 0) cid = 0;
        aS[tid] = cat_A[cid * 80 + tid];
    }
    __syncthreads();
    const int j = tid;
    const int v = j >> 5, slot = j & 31;
    float acc = svT[(size_t)c * 320 + j];
    const float* row = catBVT + (size_t)c * 2560;
#pragma unroll
    for (int r = 0; r < 8; ++r)
        acc = fmaf(aS[v * 8 + r], row[(v * 8 + r) * 32 + slot], acc);
    vcT[((size_t)b * 1024 + c) * 320 + j] = f2bf(acc);
}

// ---------------------------------------------------------------------------
// cb[0:64] = kb1, cb[64:128] = vb1
// ---------------------------------------------------------------------------
__global__ void concat_bias(const float* __restrict__ a,
                            const float* __restrict__ b, float* __restrict__ o)
{
    int t = threadIdx.x;
    if (t < 64) o[t] = a[t];
    else if (t < 128) o[t] = b[t - 64];
}

__global__ void tail_zero(float* p)
{
    if (threadIdx.x < 2) p[threadIdx.x] = 0.f;
}

// ---------------------------------------------------------------------------
extern "C" void kernel_launch(void* const* d_in, const int* in_sizes, int n_in,
                              void* d_out, int out_size, void* d_ws, size_t ws_size,
                              hipStream_t stream)
{
    (void)in_sizes; (void)n_in;
    const float* x         = (const float*)d_in[0];
    const int*   cat_ids   = (const int*)  d_in[1];
    const float* sm        = (const float*)d_in[2];
    const float* cat_A     = (const float*)d_in[3];
    const float* cat_B     = (const float*)d_in[4];
    const float* cat_emb   = (const float*)d_in[5];
    const float* scale_emb = (const float*)d_in[6];
    const float* Wq        = (const float*)d_in[7];
    const float* Wk        = (const float*)d_in[8];
    const float* Wv        = (const float*)d_in[9];
    const float* aW1       = (const float*)d_in[10];
    const float* ab1       = (const float*)d_in[11];
    const float* aW2       = (const float*)d_in[12];
    const float* ab2       = (const float*)d_in[13];
    const float* kW1       = (const float*)d_in[14];
    const float* kb1       = (const float*)d_in[15];
    const float* kW2       = (const float*)d_in[16];
    const float* kb2       = (const float*)d_in[17];
    const float* vW1       = (const float*)d_in[18];
    const float* vb1       = (const float*)d_in[19];
    const float* vW2       = (const float*)d_in[20];
    const float* vb2       = (const float*)d_in[21];
    const float* gk        = (const float*)d_in[22];
    const float* gv        = (const float*)d_in[23];
    const float* log_temp  = (const float*)d_in[24];

    float* out   = (float*)d_out;
    float* memb  = out;                          // mem_bf16 then fp32 mem_k
    float* outv  = out + (size_t)21760 * 1024;   // mem_v region (hosts query_bf first)

    // ---- workspace layout (floats) ----
    float* w      = (float*)d_ws;
    u16*   kc_bf  = (u16*)w;                     // [0, 5,242,880)
    u16*   vcT_bf = (u16*)(w + 5242880);         // [5,242,880, 10,485,760)
    float* sk     = w + 10485760;                // 327,680
    float* sv     = w + 10813440;                // 327,680
    float* svT    = w + 11141120;                // 327,680
    u16*   sk_bf  = (u16*)(w + 11468800);        // 163,840 f-equiv
    u16*   svT_bf = (u16*)(w + 11632640);        // 163,840 f-equiv
    float* alph   = w + 11796480;                // 21,760
    float* logits = w + 11859200;                // 13,926,400 (ends 25,785,600)
    // tail region (alpha-path statics), after logits:
    float* tail0  = w + 25785600;
    u16*   aW1topT = (u16*)tail0;                // 65,536 f each
    u16*   aW1midT = (u16*)(tail0 + 65536);
    u16*   aW1botT = (u16*)(tail0 + 131072);
    float* ceW    = tail0 + 196608;              // 22*128
    float* seW    = tail0 + 199424;              // 10*128
    float* cb     = tail0 + 200704;              // 128
    u16*   h_bf   = (u16*)(tail0 + 200832);      // 1,392,640 f (ends w+27,379,072)
    u16*   catB_bf = (u16*)(w + 27379072);       // 1,310,720 f (ends 28,689,792)
    u16*   sm_bf  = (u16*)(w + 28689792);        // 163,840 f  (ends 28,853,632)
    u16*   ce_bf  = (u16*)(w + 28853632);        // 11,264 f   (22x1024 bf16)
    u16*   se_bf  = (u16*)(w + 28864896);        // 5,120 f    (10x1024 bf16)
    if (ws_size < (size_t)29881600 * 4) return;
    if (out_size < 2 * 21760 * 1024 + 2) return;

    // --- overlays (lifetime-disjoint with their hosts) ---
    u16*   x_bf   = (u16*)logits;                // dead before gemm_logits
    float* bufA   = logits + 5570560;            // catBK  2,621,440
    float* bufB   = bufA + 2621440;              // catBV  2,621,440
    float* catBVT = bufB + 2621440;              // 2,621,440
    u16*   WqT    = (u16*)w;                     // dead before build_kc
    u16*   WkT    = WqT + 1048576;
    u16*   WvT    = WkT + 1048576;
    u16*   kW1T   = (u16*)sv;                    // written after sv consumed
    u16*   vW1T   = kW1T + 65536;                // contiguous => [128][1024]
    u16*   kW2T   = vW1T + 65536;
    u16*   vW2T   = kW2T + 65536;
    u16*   bufAB_bf = (u16*)w;                   // [21760][128] bf16, <= kc region
    u16*   mem_bf = (u16*)memb;                  // bf16 mem in d_out first half
    u16*   query_bf = (u16*)outv;                // dead before final mem_v gemm

    const dim3 blk256(256);

    // 0. casts / weight transposes (tcast grid = (Cc/32, R/32))
    castbf<<<dim3(2048), blk256, 0, stream>>>(x, x_bf, 21760 * 1024 / 4);
    castbf<<<dim3(320), blk256, 0, stream>>>(sm, sm_bf, 320 * 1024 / 4);
    castbf<<<dim3(2048), blk256, 0, stream>>>(cat_B, catB_bf, 2560 * 1024 / 4);
    castbf<<<dim3(22), blk256, 0, stream>>>(cat_emb, ce_bf, 22 * 1024 / 4);
    castbf<<<dim3(10), blk256, 0, stream>>>(scale_emb, se_bf, 10 * 1024 / 4);
    tcast<<<dim3(32, 32), blk256, 0, stream>>>(Wq, WqT, 1024, 1024);
    tcast<<<dim3(32, 32), blk256, 0, stream>>>(Wk, WkT, 1024, 1024);
    tcast<<<dim3(32, 32), blk256, 0, stream>>>(Wv, WvT, 1024, 1024);
    tcast<<<dim3(4, 32), blk256, 0, stream>>>(aW1,              aW1topT, 1024, 128);
    tcast<<<dim3(4, 32), blk256, 0, stream>>>(aW1 + 1024 * 128, aW1midT, 1024, 128);
    tcast<<<dim3(4, 32), blk256, 0, stream>>>(aW1 + 2048 * 128, aW1botT, 1024, 128);

    // 1. projections (MFMA, pipelined gload staging); grid = (n_blocks, m_blocks)
    gemm_mfma<1><<<dim3(8, 170), blk256, 0, stream>>>(x_bf,    WqT, (float*)query_bf, 21760, 1024, 1024, 1024, nullptr, nullptr);
    gemm_mfma<0><<<dim3(8, 3),   blk256, 0, stream>>>(sm_bf,   WkT, sk,   320,  1024, 1024, 1024, nullptr, nullptr);
    gemm_mfma<0><<<dim3(8, 3),   blk256, 0, stream>>>(sm_bf,   WvT, sv,   320,  1024, 1024, 1024, nullptr, nullptr);
    gemm_mfma<0><<<dim3(8, 20),  blk256, 0, stream>>>(catB_bf, WkT, bufA, 2560, 1024, 1024, 1024, nullptr, nullptr);
    gemm_mfma<0><<<dim3(8, 20),  blk256, 0, stream>>>(catB_bf, WvT, bufB, 2560, 1024, 1024, 1024, nullptr, nullptr);

    // 1b. alpha-path statics (tiny, bf16-A path now)
    gemm_mfma<0><<<dim3(1, 1), blk256, 0, stream>>>(ce_bf, aW1midT, ceW, 22, 128, 1024, 1024, nullptr, nullptr);
    gemm_mfma<0><<<dim3(1, 1), blk256, 0, stream>>>(se_bf, aW1botT, seW, 10, 128, 1024, 1024, ab1, nullptr);

    // 2. derived key/value layouts
    castbf<<<dim3(320), blk256, 0, stream>>>(sk, sk_bf, 320 * 1024 / 4);
    transpose32<<<dim3(32, 10), blk256, 0, stream>>>(sv, svT, 320, 1024);
    tcast<<<dim3(32, 10), blk256, 0, stream>>>(sv, svT_bf, 320, 1024);
    transpose32<<<dim3(32, 80), blk256, 0, stream>>>(bufB, catBVT, 2560, 1024);
    // small head-weight transposes AFTER sv is consumed (they overlay sv)
    tcast<<<dim3(2, 32), blk256, 0, stream>>>(kW1, kW1T, 1024, 64);
    tcast<<<dim3(2, 32), blk256, 0, stream>>>(vW1, vW1T, 1024, 64);
    tcast<<<dim3(32, 2), blk256, 0, stream>>>(kW2, kW2T, 64, 1024);
    tcast<<<dim3(32, 2), blk256, 0, stream>>>(vW2, vW2T, 64, 1024);
    concat_bias<<<dim3(1), dim3(128), 0, stream>>>(kb1, vb1, cb);

    // 3. per-batch low-rank expanded K (row-major bf16) / V (transposed bf16)
    build_kc<<<dim3(NB, 320), blk256, 0, stream>>>(sk, bufA, cat_A, cat_ids, kc_bf);
    build_vcT<<<dim3(NB, 1024), dim3(320), 0, stream>>>(svT, catBVT, cat_A, cat_ids, vcT_bf);

    // 4. alpha gate (MFMA hidden + tiny reduce)
    gemm_halpha<<<dim3(170), blk256, 0, stream>>>(query_bf, aW1topT, ceW, seW, cat_ids, h_bf);
    alpha_reduce<<<dim3(5440), blk256, 0, stream>>>(h_bf, aW2, ab2, cat_ids, alph);

    // 5. attention as MFMA GEMMs: logits -> masked softmax (P in-place) -> PV
    gemm_logits<<<dim3(6, 5, NB), blk256, 0, stream>>>(query_bf, sk_bf, kc_bf, logits);
    softmax_kernel<<<dim3(170, NB), blk256, 0, stream>>>(logits, alph, log_temp);
    gemm_pv<<<dim3(6, 8, NB), blk256, 0, stream>>>((const u16*)logits, svT_bf, vcT_bf, mem_bf);

    // 6. final low-rank projections: fused bf16 stage-1 (N=128), two stage-2
    gemm_mfma<1><<<dim3(1, 170), blk256, 0, stream>>>(mem_bf, kW1T, (float*)bufAB_bf, 21760, 128, 1024, 1024, cb, nullptr);
    gemm_mfma<0><<<dim3(8, 170), blk256, 0, stream>>>(bufAB_bf,      kW2T, memb, 21760, 1024, 64, 128, kb2, gk);
    gemm_mfma<0><<<dim3(8, 170), blk256, 0, stream>>>(bufAB_bf + 64, vW2T, outv, 21760, 1024, 64, 128, vb2, gv);

    tail_zero<<<1, 64, 0, stream>>>(out + (size_t)2 * 21760 * 1024);
}